// Round 1
// 467.777 us; speedup vs baseline: 1.1837x; 1.1837x over previous
//
#include <hip/hip_runtime.h>
#include <math.h>

// Problem constants (match reference)
#define NP 10000
#define NB 30000
#define NEDGE 300000
#define BEDGE 8192
#define EAD 16
#define HID 64
#define GH 4
#define CW 256      // GH*HID
#define DD 128
#define SEQ 6
#define NCLS 10
#define L 2

__device__ __forceinline__ float geluf(float x){
  // jax.nn.gelu(approximate=False)
  return 0.5f * x * (1.0f + erff(x * 0.7071067811865475f));
}

__device__ __forceinline__ float b2f(unsigned short u){
  unsigned v = ((unsigned)u) << 16;
  return __int_as_float(v);
}
__device__ __forceinline__ unsigned short f2b(float f){
  unsigned x = __float_as_uint(f);
  unsigned r = x + 0x7FFF + ((x >> 16) & 1);   // round-to-nearest-even
  return (unsigned short)(r >> 16);
}

typedef __attribute__((ext_vector_type(8))) short bf16x8;
typedef __attribute__((ext_vector_type(4))) float f32x4;

// ---------------------------------------------------------------------------
// MFMA GEMM body: out_bf16[M][N] = (GELU?)(A[M][KQ] @ W[KQ][N] + bias[N])
// (device body so it can be fused into merged kernels; sWt passed from caller)
// ---------------------------------------------------------------------------
template<int KQ, int NTILES, bool A_F32, bool GELU>
__device__ __forceinline__
void mfma_gemm_body(int bid, const void* __restrict__ Av, const float* __restrict__ W,
                    const float* __restrict__ bias, unsigned short* __restrict__ out,
                    int M, unsigned short* __restrict__ sWt)
{
  constexpr int N  = NTILES * 16;
  constexpr int KP = KQ + 8;
  int t = threadIdx.x, w = t >> 6, l = t & 63;
  int c = l & 15, g = l >> 4;
  for (int idx = t; idx < KQ*N; idx += 256){
    int k = idx / N, n = idx - k*N;
    sWt[n*KP + k] = f2b(W[idx]);
  }
  __syncthreads();
  int rowbase = bid*64 + w*16;
  int arow = rowbase + c; if (arow > M-1) arow = M-1;   // clamp (no OOB reads)
  f32x4 acc[NTILES] = {};
  #pragma unroll
  for (int ks = 0; ks < KQ/32; ++ks){
    int koff = ks*32 + g*8;
    bf16x8 a;
    if constexpr (A_F32){
      const float* Af = (const float*)Av + (size_t)arow*KQ + koff;
      float4 f0 = *(const float4*)Af;
      float4 f1 = *(const float4*)(Af + 4);
      a[0]=(short)f2b(f0.x); a[1]=(short)f2b(f0.y); a[2]=(short)f2b(f0.z); a[3]=(short)f2b(f0.w);
      a[4]=(short)f2b(f1.x); a[5]=(short)f2b(f1.y); a[6]=(short)f2b(f1.z); a[7]=(short)f2b(f1.w);
    } else {
      a = *(const bf16x8*)((const unsigned short*)Av + (size_t)arow*KQ + koff);
    }
    #pragma unroll
    for (int nt = 0; nt < NTILES; ++nt){
      bf16x8 b = *(const bf16x8*)&sWt[(nt*16 + c)*KP + koff];
      acc[nt] = __builtin_amdgcn_mfma_f32_16x16x32_bf16(a, b, acc[nt], 0, 0, 0);
    }
  }
  #pragma unroll
  for (int nt = 0; nt < NTILES; ++nt){
    #pragma unroll
    for (int j = 0; j < 4; ++j){
      int row = rowbase + g*4 + j;
      if (row < M){
        int col = nt*16 + c;
        float v = acc[nt][j] + bias[col];
        if (GELU) v = geluf(v);
        out[(size_t)row*N + col] = f2b(v);
      }
    }
  }
}

// ---------------------------------------------------------------------------
// k1: edge-degree count (both dirs) || node encoders (pitcher+batter) merged.
// blocks [0, nbCount): count ; [nbCount, +nbP): pitcher enc ; rest: batter enc
// ---------------------------------------------------------------------------
__global__ __launch_bounds__(256)
void k1_count_enc(const int* __restrict__ edst, const int* __restrict__ esrc,
                  int* __restrict__ degA, int* __restrict__ degB,
                  const float* __restrict__ pit, const float* __restrict__ Wp,
                  const float* __restrict__ bp, unsigned short* __restrict__ px,
                  const float* __restrict__ bat, const float* __restrict__ Wb,
                  const float* __restrict__ bb, unsigned short* __restrict__ bx,
                  int nbCount, int nbP)
{
  __shared__ unsigned short sWt[64*136];   // N=64, KP=136
  int b = blockIdx.x;
  if (b < nbCount){
    int i = b*256 + threadIdx.x;
    if (i < NEDGE){
      atomicAdd(&degA[edst[i]], 1);
      atomicAdd(&degB[esrc[i]], 1);
    }
  } else if (b < nbCount + nbP){
    mfma_gemm_body<128,4,true,true>(b - nbCount, pit, Wp, bp, px, NP, sWt);
  } else {
    mfma_gemm_body<128,4,true,true>(b - nbCount - nbP, bat, Wb, bb, bx, NB, sWt);
  }
}

// ---------------------------------------------------------------------------
// scan: shuffle-based exclusive scan, 4 elems/thread (n % 4 == 0 here)
// ---------------------------------------------------------------------------
__device__ void scan_dev(const int* __restrict__ deg, int* __restrict__ row_start,
                         int* __restrict__ cursor, int n){
  __shared__ int wsum[16];
  __shared__ int sbase;
  int t = threadIdx.x, w = t >> 6, l = t & 63;
  if (t == 0) sbase = 0;
  __syncthreads();
  for (int base = 0; base < n; base += 4096){
    int i = base + t*4;
    int4 v = make_int4(0,0,0,0);
    if (i < n) v = *(const int4*)(deg + i);
    int tsum = v.x + v.y + v.z + v.w;
    int x = tsum;
    #pragma unroll
    for (int off = 1; off < 64; off <<= 1){
      int y = __shfl_up(x, off);
      if (l >= off) x += y;
    }
    if (l == 63) wsum[w] = x;
    __syncthreads();
    int woff = 0, tot = 0;
    #pragma unroll
    for (int ww = 0; ww < 16; ++ww){
      int wv = wsum[ww];
      if (ww < w) woff += wv;
      tot += wv;
    }
    int excl = sbase + woff + x - tsum;
    if (i < n){
      int e1 = excl + v.x, e2 = excl + v.x + v.y, e3 = excl + v.x + v.y + v.z;
      row_start[i]   = excl; cursor[i]   = excl;
      row_start[i+1] = e1;   cursor[i+1] = e1;
      row_start[i+2] = e2;   cursor[i+2] = e2;
      row_start[i+3] = e3;   cursor[i+3] = e3;
    }
    __syncthreads();
    if (t == 0) sbase += tot;
    __syncthreads();
  }
  if (t == 0) row_start[n] = sbase;
}

__global__ __launch_bounds__(1024)
void scan2_kernel(const int* __restrict__ degA, int* __restrict__ rsA, int* __restrict__ curA, int nA,
                  const int* __restrict__ degB, int* __restrict__ rsB, int* __restrict__ curB, int nB,
                  float* __restrict__ mvec){
  if (blockIdx.x == 0){
    scan_dev(degA, rsA, curA, nA);
  } else {
    if (threadIdx.x < 144) mvec[threadIdx.x] = 0.f;   // zero mvec for colsum atomics
    scan_dev(degB, rsB, curB, nB);
  }
}

// ---------------------------------------------------------------------------
// k2: CSR scatter (both dirs) || all 4 GAT projection GEMMs merged.
// ---------------------------------------------------------------------------
__global__ __launch_bounds__(256)
void k2_scatter_proj(const int* __restrict__ edst, const int* __restrict__ esrc,
                     int* __restrict__ curA, int* __restrict__ curB,
                     int2* __restrict__ csrA, int2* __restrict__ csrB,
                     const unsigned short* __restrict__ px, const unsigned short* __restrict__ bx,
                     const float* __restrict__ rel_Wl, const float* __restrict__ rel_bl,
                     const float* __restrict__ rel_Wr, const float* __restrict__ rel_br,
                     const float* __restrict__ rev_Wl, const float* __restrict__ rev_bl,
                     const float* __restrict__ rev_Wr, const float* __restrict__ rev_br,
                     unsigned short* __restrict__ xlA, unsigned short* __restrict__ xrA,
                     unsigned short* __restrict__ xlB, unsigned short* __restrict__ xrB,
                     int nbScat, int nbP, int nbB)
{
  __shared__ unsigned short sWt[256*72];   // N=256, KP=72
  int b = blockIdx.x;
  if (b < nbScat){
    int i = b*256 + threadIdx.x;
    if (i < NEDGE){
      int d = edst[i], s = esrc[i];
      int p = atomicAdd(&curA[d], 1);
      csrA[p] = make_int2(i, s);
      int q = atomicAdd(&curB[s], 1);
      csrB[q] = make_int2(i, d);
    }
  } else {
    b -= nbScat;
    if (b < nbP)               mfma_gemm_body<64,16,false,false>(b,            px, rel_Wl, rel_bl, xlA, NP, sWt);
    else if (b < nbP + nbB)    mfma_gemm_body<64,16,false,false>(b-nbP,        bx, rel_Wr, rel_br, xrA, NB, sWt);
    else if (b < nbP + 2*nbB)  mfma_gemm_body<64,16,false,false>(b-nbP-nbB,    bx, rev_Wl, rev_bl, xlB, NB, sWt);
    else                       mfma_gemm_body<64,16,false,false>(b-nbP-2*nbB,  px, rev_Wr, rev_br, xrB, NP, sWt);
  }
}

// pair-compute for gat (see kernel): updates m,s,a0..a3 from regs
#define GAT_PAIR(X0, X1, EV0, EV1, V1OK, P0MASK)                             \
  {                                                                          \
    float x0 = b2f(X0.x), x1 = b2f(X0.y), x2 = b2f(X0.z), x3 = b2f(X0.w);    \
    float y0 = b2f(X1.x), y1 = b2f(X1.y), y2 = b2f(X1.z), y3 = b2f(X1.w);    \
    float h00 = x0 + r0, h01 = x1 + r1, h02 = x2 + r2, h03 = x3 + r3;        \
    float h10 = y0 + r0, h11 = y1 + r1, h12 = y2 + r2, h13 = y3 + r3;        \
    int ia0 = __float_as_int(EV0);                                           \
    int ia1 = __float_as_int(EV1);                                           \
    _Pragma("unroll")                                                        \
    for (int k = 0; k < EAD; ++k){                                           \
      float c0 = __int_as_float(__builtin_amdgcn_readlane(ia0, k));          \
      float c1 = __int_as_float(__builtin_amdgcn_readlane(ia1, k));          \
      float4 wv = *(const float4*)&sWe[k*CW + 4*l];                          \
      h00 = fmaf(c0, wv.x, h00); h01 = fmaf(c0, wv.y, h01);                  \
      h02 = fmaf(c0, wv.z, h02); h03 = fmaf(c0, wv.w, h03);                  \
      h10 = fmaf(c1, wv.x, h10); h11 = fmaf(c1, wv.y, h11);                  \
      h12 = fmaf(c1, wv.z, h12); h13 = fmaf(c1, wv.w, h13);                  \
    }                                                                        \
    h00 = (h00 > 0.f ? h00 : 0.2f*h00) * at.x;                               \
    h01 = (h01 > 0.f ? h01 : 0.2f*h01) * at.y;                               \
    h02 = (h02 > 0.f ? h02 : 0.2f*h02) * at.z;                               \
    h03 = (h03 > 0.f ? h03 : 0.2f*h03) * at.w;                               \
    h10 = (h10 > 0.f ? h10 : 0.2f*h10) * at.x;                               \
    h11 = (h11 > 0.f ? h11 : 0.2f*h11) * at.y;                               \
    h12 = (h12 > 0.f ? h12 : 0.2f*h12) * at.z;                               \
    h13 = (h13 > 0.f ? h13 : 0.2f*h13) * at.w;                               \
    float g0 = (h00 + h01) + (h02 + h03);                                    \
    float g1 = (h10 + h11) + (h12 + h13);                                    \
    _Pragma("unroll")                                                        \
    for (int off = 1; off < 16; off <<= 1){                                  \
      g0 += __shfl_xor(g0, off);                                             \
      g1 += __shfl_xor(g1, off);                                             \
    }                                                                        \
    float gm = (V1OK) ? fmaxf(g0, g1) : g0;                                  \
    float mn = fmaxf(m, gm);                                                 \
    float cc = __expf(m - mn);                                               \
    float p0 = __expf(g0 - mn);                                              \
    if (!(P0MASK)) p0 = 0.f;                                                 \
    float p1 = (V1OK) ? __expf(g1 - mn) : 0.f;                               \
    s  = fmaf(s, cc, p0 + p1);                                               \
    a0 = fmaf(a0, cc, fmaf(p1, y0, p0*x0));                                  \
    a1 = fmaf(a1, cc, fmaf(p1, y1, p0*x1));                                  \
    a2 = fmaf(a2, cc, fmaf(p1, y2, p0*x2));                                  \
    a3 = fmaf(a3, cc, fmaf(p1, y3, p0*x3));                                  \
    m = mn;                                                                  \
  }

// ---------------------------------------------------------------------------
// Merged fused GATv2 for BOTH directions in one launch (blockIdx partition).
// One WAVE per destination, rotation-free 2x-unrolled double buffer (as R12).
// ---------------------------------------------------------------------------
__global__ __launch_bounds__(256)
void gat2_kernel(const unsigned short* __restrict__ xlA_, const unsigned short* __restrict__ xrA_,
                 const float* __restrict__ WeA, const float* __restrict__ attA,
                 const float* __restrict__ biasA, const int2* __restrict__ csrA_,
                 const int* __restrict__ rsA_, float* __restrict__ houtA,
                 const unsigned short* __restrict__ xlB_, const unsigned short* __restrict__ xrB_,
                 const float* __restrict__ WeB, const float* __restrict__ attB,
                 const float* __restrict__ biasB, const int2* __restrict__ csrB_,
                 const int* __restrict__ rsB_, float* __restrict__ houtB,
                 const float* __restrict__ ea, int gsplit)
{
  __shared__ float sWe[16*CW];
  bool isA = (int)blockIdx.x < gsplit;
  const unsigned short* xl = isA ? xlA_ : xlB_;
  const unsigned short* xr = isA ? xrA_ : xrB_;
  const float* We   = isA ? WeA   : WeB;
  const float* att  = isA ? attA  : attB;
  const float* bias = isA ? biasA : biasB;
  const int2* csr   = isA ? csrA_ : csrB_;
  const int* row_start = isA ? rsA_ : rsB_;
  float* hout = isA ? houtA : houtB;
  int ndst = isA ? NB : NP;
  int bid  = isA ? (int)blockIdx.x : (int)blockIdx.x - gsplit;
  int nblk = isA ? gsplit : (int)gridDim.x - gsplit;

  int t = threadIdx.x, l = t & 63;
  for (int i = t*4; i < 16*CW; i += 1024)
    *(float4*)&sWe[i] = *(const float4*)&We[i];
  __syncthreads();
  float4 at = *(const float4*)&att[4*l];
  float4 bi = *(const float4*)&bias[(l & 15)*4];
  int wid = bid*4 + (t >> 6);
  int nw = nblk*4;
  for (int d = wid; d < ndst; d += nw){
    ushort4 ru = *(const ushort4*)(xr + (size_t)d*CW + 4*l);
    float r0 = b2f(ru.x), r1 = b2f(ru.y), r2 = b2f(ru.z), r3 = b2f(ru.w);
    int rs = row_start[d], re = row_start[d+1];
    float m = -INFINITY, s = 0.f;
    float a0 = 0.f, a1 = 0.f, a2 = 0.f, a3 = 0.f;
    if (rs < re){
      int last = re - 1;
      #define CLMP(x) ((x) > last ? last : (x))
      int2 qA0 = csr[rs],         qA1 = csr[CLMP(rs+1)];
      int2 qB0 = csr[CLMP(rs+2)], qB1 = csr[CLMP(rs+3)];
      int2 nA0 = csr[CLMP(rs+4)], nA1 = csr[CLMP(rs+5)];
      int2 nB0 = csr[CLMP(rs+6)], nB1 = csr[CLMP(rs+7)];
      ushort4 xA0 = *(const ushort4*)(xl + (size_t)qA0.y*CW + 4*l);
      ushort4 xA1 = *(const ushort4*)(xl + (size_t)qA1.y*CW + 4*l);
      float  evA0 = ea[(size_t)qA0.x*EAD + (l & 15)];
      float  evA1 = ea[(size_t)qA1.x*EAD + (l & 15)];
      ushort4 xB0 = *(const ushort4*)(xl + (size_t)qB0.y*CW + 4*l);
      ushort4 xB1 = *(const ushort4*)(xl + (size_t)qB1.y*CW + 4*l);
      float  evB0 = ea[(size_t)qB0.x*EAD + (l & 15)];
      float  evB1 = ea[(size_t)qB1.x*EAD + (l & 15)];
      for (int i = rs; i < re; i += 4){
        int2 mA0 = csr[CLMP(i+8)],  mA1 = csr[CLMP(i+9)];
        int2 mB0 = csr[CLMP(i+10)], mB1 = csr[CLMP(i+11)];
        GAT_PAIR(xA0, xA1, evA0, evA1, (i+1 < re), true);
        xA0 = *(const ushort4*)(xl + (size_t)nA0.y*CW + 4*l);
        xA1 = *(const ushort4*)(xl + (size_t)nA1.y*CW + 4*l);
        evA0 = ea[(size_t)nA0.x*EAD + (l & 15)];
        evA1 = ea[(size_t)nA1.x*EAD + (l & 15)];
        nA0 = mA0; nA1 = mA1;
        GAT_PAIR(xB0, xB1, evB0, evB1, (i+3 < re), (i+2 < re));
        xB0 = *(const ushort4*)(xl + (size_t)nB0.y*CW + 4*l);
        xB1 = *(const ushort4*)(xl + (size_t)nB1.y*CW + 4*l);
        evB0 = ea[(size_t)nB0.x*EAD + (l & 15)];
        evB1 = ea[(size_t)nB1.x*EAD + (l & 15)];
        nB0 = mB0; nB1 = mB1;
      }
      #undef CLMP
    }
    float inv = 1.f / (s + 1e-16f);
    float v0 = a0*inv, v1 = a1*inv, v2 = a2*inv, v3 = a3*inv;
    v0 += __shfl_xor(v0, 16); v1 += __shfl_xor(v1, 16);
    v2 += __shfl_xor(v2, 16); v3 += __shfl_xor(v3, 16);
    v0 += __shfl_xor(v0, 32); v1 += __shfl_xor(v1, 32);
    v2 += __shfl_xor(v2, 32); v3 += __shfl_xor(v3, 32);
    if (l < 16){
      float4 o;
      o.x = geluf(v0*0.25f + bi.x);
      o.y = geluf(v1*0.25f + bi.y);
      o.z = geluf(v2*0.25f + bi.z);
      o.w = geluf(v3*0.25f + bi.w);
      *(float4*)(hout + (size_t)d*HID + 4*l) = o;
    }
  }
}

// ---------------------------------------------------------------------------
// k3: fused column means (mvec) || token-gather GEMM (cat -> @Wet) merged.
// ---------------------------------------------------------------------------
__device__ __forceinline__ void colsum_seg(int bid, int nb, const float4* __restrict__ in4,
                                           long total4, int n4, float* __restrict__ out,
                                           float scale, float* lds){
  int t = threadIdx.x, l = t & 63, w = t >> 6;
  long gid = (long)bid*256 + t;
  long stride = (long)nb*256;
  float4 acc = make_float4(0.f,0.f,0.f,0.f);
  for (long i = gid; i < total4; i += stride){
    float4 v = in4[i];
    acc.x += v.x; acc.y += v.y; acc.z += v.z; acc.w += v.w;
  }
  for (int off = n4; off < 64; off <<= 1){
    acc.x += __shfl_xor(acc.x, off);
    acc.y += __shfl_xor(acc.y, off);
    acc.z += __shfl_xor(acc.z, off);
    acc.w += __shfl_xor(acc.w, off);
  }
  if (l < n4) *(float4*)&lds[(w*n4 + l)*4] = acc;
  __syncthreads();
  if (t < n4*4){
    float sum = lds[t] + lds[n4*4 + t] + lds[2*n4*4 + t] + lds[3*n4*4 + t];
    atomicAdd(&out[t], sum * scale);
  }
  __syncthreads();
}

__device__ void colsum3_body(int bid, int nb, const float* __restrict__ hp,
                             const float* __restrict__ hb, const float* __restrict__ ea,
                             float* __restrict__ mvec){
  __shared__ float lds[4*16*4];
  colsum_seg(bid, nb, (const float4*)ea, (long)NEDGE*EAD/4, 4,  mvec+128, 1.f/NEDGE, lds);
  colsum_seg(bid, nb, (const float4*)hb, (long)NB*HID/4,    16, mvec+64,  1.f/NB,    lds);
  colsum_seg(bid, nb, (const float4*)hp, (long)NP*HID/4,    16, mvec,     1.f/NP,    lds);
}

__device__ void gemmcat_body(int bid, const float* __restrict__ hp, const float* __restrict__ hb,
                             const float* __restrict__ ea, const int* __restrict__ esrc,
                             const int* __restrict__ edst, const int* __restrict__ eids,
                             const float* __restrict__ W, const float* __restrict__ bias,
                             float* __restrict__ out)
{
  // M=BEDGE, K=144, N=128 ; A row = concat(hp[src], hb[dst], ea[e]) gathered on the fly
  __shared__ float sAT[16][68];
  __shared__ float sB[16][68];
  __shared__ int sS[64], sD[64], sE[64];
  int t = threadIdx.x;
  int m0 = (bid >> 1)*64, n0 = (bid & 1)*64;
  if (t < 64){
    int e = eids[m0 + t];
    sS[t] = esrc[e]; sD[t] = edst[e]; sE[t] = e;
  }
  __syncthreads();
  int tr = t >> 4, tc = t & 15;
  float acc[4][4] = {};
  for (int k0 = 0; k0 < 144; k0 += 16){
    {
      int r = t >> 2, c = (t & 3) * 4;
      const float* src; int col = k0 + c;
      if (k0 < 64)       { src = hp + (size_t)sS[r]*HID; }
      else if (k0 < 128) { src = hb + (size_t)sD[r]*HID; col -= 64; }
      else               { src = ea + (size_t)sE[r]*EAD; col -= 128; }
      float4 va = *(const float4*)(src + col);
      sAT[c+0][r] = va.x; sAT[c+1][r] = va.y; sAT[c+2][r] = va.z; sAT[c+3][r] = va.w;
    }
    {
      int r = t >> 4, c = (t & 15) * 4;
      float4 vb = *(const float4*)(W + (size_t)(k0+r)*DD + n0 + c);
      *(float4*)&sB[r][c] = vb;
    }
    __syncthreads();
    #pragma unroll
    for (int k = 0; k < 16; ++k){
      float4 av = *(const float4*)&sAT[k][tr*4];
      float4 bv = *(const float4*)&sB[k][tc*4];
      acc[0][0] = fmaf(av.x, bv.x, acc[0][0]);
      acc[0][1] = fmaf(av.x, bv.y, acc[0][1]);
      acc[0][2] = fmaf(av.x, bv.z, acc[0][2]);
      acc[0][3] = fmaf(av.x, bv.w, acc[0][3]);
      acc[1][0] = fmaf(av.y, bv.x, acc[1][0]);
      acc[1][1] = fmaf(av.y, bv.y, acc[1][1]);
      acc[1][2] = fmaf(av.y, bv.z, acc[1][2]);
      acc[1][3] = fmaf(av.y, bv.w, acc[1][3]);
      acc[2][0] = fmaf(av.z, bv.x, acc[2][0]);
      acc[2][1] = fmaf(av.z, bv.y, acc[2][1]);
      acc[2][2] = fmaf(av.z, bv.z, acc[2][2]);
      acc[2][3] = fmaf(av.z, bv.w, acc[2][3]);
      acc[3][0] = fmaf(av.w, bv.x, acc[3][0]);
      acc[3][1] = fmaf(av.w, bv.y, acc[3][1]);
      acc[3][2] = fmaf(av.w, bv.z, acc[3][2]);
      acc[3][3] = fmaf(av.w, bv.w, acc[3][3]);
    }
    __syncthreads();
  }
  #pragma unroll
  for (int i = 0; i < 4; ++i){
    int gr = m0 + tr*4 + i;
    float4 v;
    v.x = acc[i][0] + bias[n0 + tc*4 + 0];
    v.y = acc[i][1] + bias[n0 + tc*4 + 1];
    v.z = acc[i][2] + bias[n0 + tc*4 + 2];
    v.w = acc[i][3] + bias[n0 + tc*4 + 3];
    *(float4*)(out + (size_t)gr*DD + n0 + tc*4) = v;
  }
}

__global__ __launch_bounds__(256)
void k3_colsum_gemmcat(const float* __restrict__ hp, const float* __restrict__ hb,
                       const float* __restrict__ ea, float* __restrict__ mvec,
                       const int* __restrict__ esrc, const int* __restrict__ edst,
                       const int* __restrict__ eids, const float* __restrict__ Wet,
                       const float* __restrict__ bet, float* __restrict__ tokb,
                       int nbCol)
{
  int b = blockIdx.x;
  if (b < nbCol) colsum3_body(b, nbCol, hp, hb, ea, mvec);
  else           gemmcat_body(b - nbCol, hp, hb, ea, esrc, edst, eids, Wet, bet, tokb);
}

// ---------------------------------------------------------------------------
// Fused transformer: buildx + 2 encoder layers + ctxdot in ONE block (512 thr).
// All data is 6x128; weights (~1.6MB) streamed from L2/L3. Writes only bias2.
// ---------------------------------------------------------------------------
__global__ __launch_bounds__(512)
void xform_kernel(const float* __restrict__ hist, const float* __restrict__ mvec,
                  const float* __restrict__ Wgs, const float* __restrict__ bgs,
                  const float* __restrict__ pos,
                  const float* __restrict__ Wqkv, const float* __restrict__ bqkv,
                  const float* __restrict__ Wo, const float* __restrict__ bo,
                  const float* __restrict__ ln1g, const float* __restrict__ ln1b,
                  const float* __restrict__ W1, const float* __restrict__ b1,
                  const float* __restrict__ W2, const float* __restrict__ b2,
                  const float* __restrict__ ln2g, const float* __restrict__ ln2b,
                  const float* __restrict__ Wc1, const float* __restrict__ bc1,
                  float* __restrict__ bias2)
{
  __shared__ float sx[SEQ*DD];       // current x
  __shared__ float sq[SEQ*3*DD];     // qkv
  __shared__ float sh[SEQ*512];      // ffn hidden / pre-LN1 buffer
  __shared__ float st[SEQ*DD];       // attn-out / pre-LN2 buffer
  __shared__ float sc[4][6][6];
  __shared__ float smean[SEQ], sinv[SEQ];
  int t = threadIdx.x;

  // build x: rows 0..4 = hist+pos ; row 5 = mvec@Wgs + bgs + pos[5]
  for (int i = t; i < (SEQ-1)*DD; i += 512) sx[i] = hist[i] + pos[i];
  if (t < DD){
    float acc = bgs[t];
    #pragma unroll 4
    for (int k = 0; k < 144; ++k) acc = fmaf(mvec[k], Wgs[k*DD + t], acc);
    sx[(SEQ-1)*DD + t] = acc + pos[(SEQ-1)*DD + t];
  }
  __syncthreads();

  for (int lyr = 0; lyr < L; ++lyr){
    // qkv = x @ Wqkv + bqkv
    const float* wq = Wqkv + (size_t)lyr*DD*3*DD;
    const float* bq = bqkv + lyr*3*DD;
    for (int i = t; i < SEQ*3*DD; i += 512){
      int s = i / 384, n = i - s*384;
      float acc = bq[n];
      const float* xr = &sx[s*DD];
      #pragma unroll 8
      for (int k = 0; k < DD; ++k) acc = fmaf(xr[k], wq[(size_t)k*384 + n], acc);
      sq[i] = acc;
    }
    __syncthreads();
    // scores
    if (t < 144){
      int h = t/36, r = t%36, qi = r/6, ki = r%6;
      float acc = 0.f;
      #pragma unroll
      for (int d2 = 0; d2 < 32; ++d2)
        acc = fmaf(sq[qi*384 + h*32 + d2], sq[ki*384 + 128 + h*32 + d2], acc);
      sc[h][qi][ki] = acc * 0.17677669529663687f;
    }
    __syncthreads();
    if (t < 24){
      int h = t/6, qi = t%6;
      float* row = sc[h][qi];
      float mx = row[0];
      #pragma unroll
      for (int k = 1; k < 6; ++k) mx = fmaxf(mx, row[k]);
      float sm = 0.f;
      #pragma unroll
      for (int k = 0; k < 6; ++k){ row[k] = __expf(row[k]-mx); sm += row[k]; }
      float inv = 1.f/sm;
      #pragma unroll
      for (int k = 0; k < 6; ++k) row[k] *= inv;
    }
    __syncthreads();
    // attention output -> st
    for (int i = t; i < SEQ*DD; i += 512){
      int s = i >> 7, n = i & 127, h = n >> 5, d2 = n & 31;
      float acc = 0.f;
      #pragma unroll
      for (int ki = 0; ki < 6; ++ki)
        acc = fmaf(sc[h][s][ki], sq[ki*384 + 256 + h*32 + d2], acc);
      st[i] = acc;
    }
    __syncthreads();
    // proj + residual -> sh[0..767]
    const float* wo = Wo + (size_t)lyr*DD*DD;
    const float* bop = bo + lyr*DD;
    for (int i = t; i < SEQ*DD; i += 512){
      int s = i >> 7, n = i & 127;
      float acc = bop[n] + sx[i];
      const float* ar = &st[s*DD];
      #pragma unroll 8
      for (int k = 0; k < DD; ++k) acc = fmaf(ar[k], wo[(size_t)k*DD + n], acc);
      sh[i] = acc;
    }
    __syncthreads();
    // LN1: sh -> sx
    {
      int w = t >> 6, lw = t & 63;
      if (w < SEQ){
        float v0 = sh[w*DD + lw], v1 = sh[w*DD + 64 + lw];
        float sm = v0 + v1;
        #pragma unroll
        for (int off = 1; off < 64; off <<= 1) sm += __shfl_xor(sm, off);
        float mean = sm * 0.0078125f;
        float d0 = v0-mean, d1 = v1-mean;
        float q = d0*d0 + d1*d1;
        #pragma unroll
        for (int off = 1; off < 64; off <<= 1) q += __shfl_xor(q, off);
        if (lw == 0){ smean[w] = mean; sinv[w] = rsqrtf(q*0.0078125f + 1e-5f); }
      }
    }
    __syncthreads();
    {
      const float* g = ln1g + lyr*DD; const float* be = ln1b + lyr*DD;
      for (int i = t; i < SEQ*DD; i += 512){
        int s = i >> 7, n = i & 127;
        sx[i] = (sh[i]-smean[s])*sinv[s]*g[n] + be[n];
      }
    }
    __syncthreads();
    // ffn1 -> sh[6][512]
    const float* w1 = W1 + (size_t)lyr*DD*512;
    const float* b1p = b1 + lyr*512;
    for (int i = t; i < SEQ*512; i += 512){
      int s = i >> 9, n = i & 511;
      float acc = b1p[n];
      const float* xr2 = &sx[s*DD];
      #pragma unroll 8
      for (int k = 0; k < DD; ++k) acc = fmaf(xr2[k], w1[(size_t)k*512 + n], acc);
      sh[i] = geluf(acc);
    }
    __syncthreads();
    // ffn2 + residual -> st
    const float* w2 = W2 + (size_t)lyr*512*DD;
    const float* b2p = b2 + lyr*DD;
    for (int i = t; i < SEQ*DD; i += 512){
      int s = i >> 7, n = i & 127;
      float acc = b2p[n] + sx[i];
      const float* hr = &sh[s*512];
      #pragma unroll 8
      for (int k = 0; k < 512; ++k) acc = fmaf(hr[k], w2[(size_t)k*DD + n], acc);
      st[i] = acc;
    }
    __syncthreads();
    // LN2: st -> sx
    {
      int w = t >> 6, lw = t & 63;
      if (w < SEQ){
        float v0 = st[w*DD + lw], v1 = st[w*DD + 64 + lw];
        float sm = v0 + v1;
        #pragma unroll
        for (int off = 1; off < 64; off <<= 1) sm += __shfl_xor(sm, off);
        float mean = sm * 0.0078125f;
        float d0 = v0-mean, d1 = v1-mean;
        float q = d0*d0 + d1*d1;
        #pragma unroll
        for (int off = 1; off < 64; off <<= 1) q += __shfl_xor(q, off);
        if (lw == 0){ smean[w] = mean; sinv[w] = rsqrtf(q*0.0078125f + 1e-5f); }
      }
    }
    __syncthreads();
    {
      const float* g = ln2g + lyr*DD; const float* be = ln2b + lyr*DD;
      for (int i = t; i < SEQ*DD; i += 512){
        int s = i >> 7, n = i & 127;
        sx[i] = (st[i]-smean[s])*sinv[s]*g[n] + be[n];
      }
    }
    __syncthreads();
  }
  // ctxdot: bias2[n] = bc1[n] + sum_k ctx[k] * Wc1[(128+k)][n]
  if (t < DD){
    float acc = bc1[t];
    const float* ctx = &sx[(SEQ-1)*DD];
    #pragma unroll 4
    for (int k = 0; k < DD; ++k) acc = fmaf(ctx[k], Wc1[(size_t)(DD + k)*DD + t], acc);
    bias2[t] = acc;
  }
}

// ---------------------------------------------------------------------------
// Tiled GEMM (f32): hid = gelu(tokb @ Wc1[0:128] + bias2)
// ---------------------------------------------------------------------------
template<bool GELU>
__global__ __launch_bounds__(256)
void gemm64_kernel(const float* __restrict__ A, const float* __restrict__ W,
                   const float* __restrict__ bias, float* __restrict__ out,
                   int M, int K, int N)
{
  __shared__ float sAT[16][68];
  __shared__ float sB[16][68];
  int t = threadIdx.x;
  int m0 = blockIdx.x * 64, n0 = blockIdx.y * 64;
  int tr = t >> 4, tc = t & 15;
  float acc[4][4] = {};
  for (int k0 = 0; k0 < K; k0 += 16){
    {
      int r = t >> 2, c = (t & 3) * 4;
      int gr = m0 + r;
      float4 va = make_float4(0.f,0.f,0.f,0.f);
      if (gr < M) va = *(const float4*)(A + (size_t)gr*K + k0 + c);
      sAT[c+0][r] = va.x; sAT[c+1][r] = va.y; sAT[c+2][r] = va.z; sAT[c+3][r] = va.w;
    }
    {
      int r = t >> 4, c = (t & 15) * 4;
      float4 vb = *(const float4*)(W + (size_t)(k0+r)*N + n0 + c);
      *(float4*)&sB[r][c] = vb;
    }
    __syncthreads();
    #pragma unroll
    for (int k = 0; k < 16; ++k){
      float4 av = *(const float4*)&sAT[k][tr*4];
      float4 bv = *(const float4*)&sB[k][tc*4];
      acc[0][0] = fmaf(av.x, bv.x, acc[0][0]);
      acc[0][1] = fmaf(av.x, bv.y, acc[0][1]);
      acc[0][2] = fmaf(av.x, bv.z, acc[0][2]);
      acc[0][3] = fmaf(av.x, bv.w, acc[0][3]);
      acc[1][0] = fmaf(av.y, bv.x, acc[1][0]);
      acc[1][1] = fmaf(av.y, bv.y, acc[1][1]);
      acc[1][2] = fmaf(av.y, bv.z, acc[1][2]);
      acc[1][3] = fmaf(av.y, bv.w, acc[1][3]);
      acc[2][0] = fmaf(av.z, bv.x, acc[2][0]);
      acc[2][1] = fmaf(av.z, bv.y, acc[2][1]);
      acc[2][2] = fmaf(av.z, bv.z, acc[2][2]);
      acc[2][3] = fmaf(av.z, bv.w, acc[2][3]);
      acc[3][0] = fmaf(av.w, bv.x, acc[3][0]);
      acc[3][1] = fmaf(av.w, bv.y, acc[3][1]);
      acc[3][2] = fmaf(av.w, bv.z, acc[3][2]);
      acc[3][3] = fmaf(av.w, bv.w, acc[3][3]);
    }
    __syncthreads();
  }
  #pragma unroll
  for (int i = 0; i < 4; ++i){
    int gr = m0 + tr*4 + i;
    if (gr < M){
      float4 v;
      v.x = acc[i][0] + bias[n0 + tc*4 + 0];
      v.y = acc[i][1] + bias[n0 + tc*4 + 1];
      v.z = acc[i][2] + bias[n0 + tc*4 + 2];
      v.w = acc[i][3] + bias[n0 + tc*4 + 3];
      if (GELU){ v.x = geluf(v.x); v.y = geluf(v.y); v.z = geluf(v.z); v.w = geluf(v.w); }
      *(float4*)(out + (size_t)gr*N + n0 + tc*4) = v;
    }
  }
}

// out[i] = hid[i] @ Wc2 + bc2  (N=10), float4 hid reads
__global__ void head2_kernel(const float* __restrict__ hid, const float* __restrict__ Wc2,
                             const float* __restrict__ bc2, float* __restrict__ out){
  int i = blockIdx.x*blockDim.x + threadIdx.x;
  if (i >= BEDGE*16) return;
  int tok = i >> 4, c = i & 15;
  if (c < NCLS){
    float acc = bc2[c];
    const float4* hr4 = (const float4*)(hid + (size_t)tok*DD);
    #pragma unroll 8
    for (int k4 = 0; k4 < 32; ++k4){
      float4 hv = hr4[k4];
      acc = fmaf(hv.x, Wc2[(4*k4+0)*NCLS + c], acc);
      acc = fmaf(hv.y, Wc2[(4*k4+1)*NCLS + c], acc);
      acc = fmaf(hv.z, Wc2[(4*k4+2)*NCLS + c], acc);
      acc = fmaf(hv.w, Wc2[(4*k4+3)*NCLS + c], acc);
    }
    out[tok*NCLS + c] = acc;
  }
}

extern "C" void kernel_launch(void* const* d_in, const int* in_sizes, int n_in,
                              void* d_out, int out_size, void* d_ws, size_t ws_size,
                              hipStream_t stream){
  (void)in_sizes; (void)n_in; (void)out_size; (void)ws_size;
  const float* pitcher = (const float*)d_in[0];
  const float* batter  = (const float*)d_in[1];
  const float* eattr   = (const float*)d_in[2];
  const float* hist    = (const float*)d_in[3];
  const float* Wp = (const float*)d_in[4];
  const float* bp = (const float*)d_in[5];
  const float* Wb = (const float*)d_in[6];
  const float* bb = (const float*)d_in[7];
  const float* rel_Wl  = (const float*)d_in[8];
  const float* rel_bl  = (const float*)d_in[9];
  const float* rel_Wr  = (const float*)d_in[10];
  const float* rel_br  = (const float*)d_in[11];
  const float* rel_We  = (const float*)d_in[12];
  const float* rel_att = (const float*)d_in[13];
  const float* rel_bias= (const float*)d_in[14];
  const float* rev_Wl  = (const float*)d_in[15];
  const float* rev_bl  = (const float*)d_in[16];
  const float* rev_Wr  = (const float*)d_in[17];
  const float* rev_br  = (const float*)d_in[18];
  const float* rev_We  = (const float*)d_in[19];
  const float* rev_att = (const float*)d_in[20];
  const float* rev_bias= (const float*)d_in[21];
  const float* Wgs = (const float*)d_in[22];
  const float* bgs = (const float*)d_in[23];
  const float* Wet = (const float*)d_in[24];
  const float* bet = (const float*)d_in[25];
  const float* pos = (const float*)d_in[26];
  const float* Wqkv= (const float*)d_in[27];
  const float* bqkv= (const float*)d_in[28];
  const float* Wo  = (const float*)d_in[29];
  const float* bo  = (const float*)d_in[30];
  const float* ln1g= (const float*)d_in[31];
  const float* ln1b= (const float*)d_in[32];
  const float* W1  = (const float*)d_in[33];
  const float* b1  = (const float*)d_in[34];
  const float* W2  = (const float*)d_in[35];
  const float* b2  = (const float*)d_in[36];
  const float* ln2g= (const float*)d_in[37];
  const float* ln2b= (const float*)d_in[38];
  const float* Wc1 = (const float*)d_in[39];
  const float* bc1 = (const float*)d_in[40];
  const float* Wc2 = (const float*)d_in[41];
  const float* bc2 = (const float*)d_in[42];
  const int* esrc = (const int*)d_in[43];
  const int* edst = (const int*)d_in[44];
  const int* eids = (const int*)d_in[45];

  // workspace carve-out
  char* w = (char*)d_ws;
  size_t off = 0;
  auto alloc = [&](size_t bytes)->void*{
    void* p = (void*)(w + off);
    off += (bytes + 255) & ~(size_t)255;
    return p;
  };
  unsigned short* px_bf  = (unsigned short*)alloc((size_t)NP*HID*2);
  unsigned short* bx_bf  = (unsigned short*)alloc((size_t)NB*HID*2);
  float*          hp     = (float*)alloc((size_t)NP*HID*4);
  float*          hb     = (float*)alloc((size_t)NB*HID*4);
  unsigned short* xlA    = (unsigned short*)alloc((size_t)NP*CW*2);  // rel: src=pitcher
  unsigned short* xrA    = (unsigned short*)alloc((size_t)NB*CW*2);  // rel: dst=batter
  unsigned short* xlB    = (unsigned short*)alloc((size_t)NB*CW*2);  // rev: src=batter
  unsigned short* xrB    = (unsigned short*)alloc((size_t)NP*CW*2);  // rev: dst=pitcher
  int*            degAB  = (int*)alloc((size_t)(NB+NP)*4);
  int*            degA   = degAB;
  int*            degB   = degAB + NB;
  int*            rowstA = (int*)alloc((size_t)(NB+1)*4);
  int*            rowstB = (int*)alloc((size_t)(NP+1)*4);
  int*            cursA  = (int*)alloc((size_t)NB*4);
  int*            cursB  = (int*)alloc((size_t)NP*4);
  int2*           csrA   = (int2*)alloc((size_t)NEDGE*8);
  int2*           csrB   = (int2*)alloc((size_t)NEDGE*8);
  float*          mvec   = (float*)alloc(144*4);
  float*          bias2  = (float*)alloc(DD*4);
  // aliases over dead GAT buffers (xlA/xrA dead after gat2):
  float*          tokb   = (float*)xlA;   // BEDGE*DD*4 = 4.19MB <= 5.12MB
  float*          hid    = (float*)xrA;   // BEDGE*DD*4 <= 15.36MB

  const int nbCount = (NEDGE + 255)/256;          // 1172
  const int nbP = (NP + 63)/64;                   // 157
  const int nbB = (NB + 63)/64;                   // 469

  // k1: degree count (both dirs) || node encoders
  hipMemsetAsync(degAB, 0, (size_t)(NB+NP)*4, stream);
  k1_count_enc<<<nbCount + nbP + nbB, 256, 0, stream>>>(
      edst, esrc, degA, degB,
      pitcher, Wp, bp, px_bf, batter, Wb, bb, bx_bf, nbCount, nbP);

  // scan both CSRs (2 blocks) + zero mvec
  scan2_kernel<<<2, 1024, 0, stream>>>(degA, rowstA, cursA, NB,
                                       degB, rowstB, cursB, NP, mvec);

  // k2: CSR scatter || all four projection GEMMs
  k2_scatter_proj<<<nbCount + 2*nbP + 2*nbB, 256, 0, stream>>>(
      edst, esrc, cursA, cursB, csrA, csrB, px_bf, bx_bf,
      rel_Wl, rel_bl, rel_Wr, rel_br, rev_Wl, rev_bl, rev_Wr, rev_br,
      xlA, xrA, xlB, xrB, nbCount, nbP, nbB);

  // merged GAT, both directions in one launch
  gat2_kernel<<<4096, 256, 0, stream>>>(
      xlA, xrA, rel_We, rel_att, rel_bias, csrA, rowstA, hb,
      xlB, xrB, rev_We, rev_att, rev_bias, csrB, rowstB, hp,
      eattr, 2048);

  // k3: column means (mvec) || token-gather GEMM (tokb = cat @ Wet + bet)
  k3_colsum_gemmcat<<<512, 256, 0, stream>>>(
      hp, hb, eattr, mvec, esrc, edst, eids, Wet, bet, tokb, 256);

  // fused transformer (buildx + 2 layers + ctxdot) -> bias2
  xform_kernel<<<1, 512, 0, stream>>>(
      hist, mvec, Wgs, bgs, pos, Wqkv, bqkv, Wo, bo, ln1g, ln1b,
      W1, b1, W2, b2, ln2g, ln2b, Wc1, bc1, bias2);

  // classifier
  gemm64_kernel<true><<<dim3(BEDGE/64,2), 256, 0, stream>>>(tokb, Wc1, bias2, hid, BEDGE, DD, DD);
  head2_kernel<<<(BEDGE*16+255)/256, 256, 0, stream>>>(hid, Wc2, bc2, (float*)d_out);
}

// Round 2
// 419.170 us; speedup vs baseline: 1.3209x; 1.1160x over previous
//
#include <hip/hip_runtime.h>
#include <math.h>

// Problem constants (match reference)
#define NP 10000
#define NB 30000
#define NEDGE 300000
#define BEDGE 8192
#define EAD 16
#define HID 64
#define GH 4
#define CW 256      // GH*HID
#define DD 128
#define SEQ 6
#define NCLS 10
#define L 2

__device__ __forceinline__ float geluf(float x){
  // jax.nn.gelu(approximate=False)
  return 0.5f * x * (1.0f + erff(x * 0.7071067811865475f));
}

__device__ __forceinline__ float b2f(unsigned short u){
  unsigned v = ((unsigned)u) << 16;
  return __int_as_float(v);
}
__device__ __forceinline__ unsigned short f2b(float f){
  unsigned x = __float_as_uint(f);
  unsigned r = x + 0x7FFF + ((x >> 16) & 1);   // round-to-nearest-even
  return (unsigned short)(r >> 16);
}

typedef __attribute__((ext_vector_type(8))) short bf16x8;
typedef __attribute__((ext_vector_type(4))) float f32x4;

// ---------------------------------------------------------------------------
// MFMA GEMM body: out_bf16[M][N] = (GELU?)(A[M][KQ] @ W[KQ][N] + bias[N])
// ---------------------------------------------------------------------------
template<int KQ, int NTILES, bool A_F32, bool GELU>
__device__ __forceinline__
void mfma_gemm_body(int bid, const void* __restrict__ Av, const float* __restrict__ W,
                    const float* __restrict__ bias, unsigned short* __restrict__ out,
                    int M, unsigned short* __restrict__ sWt)
{
  constexpr int N  = NTILES * 16;
  constexpr int KP = KQ + 8;
  int t = threadIdx.x, w = t >> 6, l = t & 63;
  int c = l & 15, g = l >> 4;
  for (int idx = t; idx < KQ*N; idx += 256){
    int k = idx / N, n = idx - k*N;
    sWt[n*KP + k] = f2b(W[idx]);
  }
  __syncthreads();
  int rowbase = bid*64 + w*16;
  int arow = rowbase + c; if (arow > M-1) arow = M-1;   // clamp (no OOB reads)
  f32x4 acc[NTILES] = {};
  #pragma unroll
  for (int ks = 0; ks < KQ/32; ++ks){
    int koff = ks*32 + g*8;
    bf16x8 a;
    if constexpr (A_F32){
      const float* Af = (const float*)Av + (size_t)arow*KQ + koff;
      float4 f0 = *(const float4*)Af;
      float4 f1 = *(const float4*)(Af + 4);
      a[0]=(short)f2b(f0.x); a[1]=(short)f2b(f0.y); a[2]=(short)f2b(f0.z); a[3]=(short)f2b(f0.w);
      a[4]=(short)f2b(f1.x); a[5]=(short)f2b(f1.y); a[6]=(short)f2b(f1.z); a[7]=(short)f2b(f1.w);
    } else {
      a = *(const bf16x8*)((const unsigned short*)Av + (size_t)arow*KQ + koff);
    }
    #pragma unroll
    for (int nt = 0; nt < NTILES; ++nt){
      bf16x8 b = *(const bf16x8*)&sWt[(nt*16 + c)*KP + koff];
      acc[nt] = __builtin_amdgcn_mfma_f32_16x16x32_bf16(a, b, acc[nt], 0, 0, 0);
    }
  }
  #pragma unroll
  for (int nt = 0; nt < NTILES; ++nt){
    #pragma unroll
    for (int j = 0; j < 4; ++j){
      int row = rowbase + g*4 + j;
      if (row < M){
        int col = nt*16 + c;
        float v = acc[nt][j] + bias[col];
        if (GELU) v = geluf(v);
        out[(size_t)row*N + col] = f2b(v);
      }
    }
  }
}

// ---------------------------------------------------------------------------
// k1: edge-degree count (both dirs) || node encoders (pitcher+batter) merged.
// ---------------------------------------------------------------------------
__global__ __launch_bounds__(256)
void k1_count_enc(const int* __restrict__ edst, const int* __restrict__ esrc,
                  int* __restrict__ degA, int* __restrict__ degB,
                  const float* __restrict__ pit, const float* __restrict__ Wp,
                  const float* __restrict__ bp, unsigned short* __restrict__ px,
                  const float* __restrict__ bat, const float* __restrict__ Wb,
                  const float* __restrict__ bb, unsigned short* __restrict__ bx,
                  int nbCount, int nbP)
{
  __shared__ unsigned short sWt[64*136];   // N=64, KP=136
  int b = blockIdx.x;
  if (b < nbCount){
    int i = b*256 + threadIdx.x;
    if (i < NEDGE){
      atomicAdd(&degA[edst[i]], 1);
      atomicAdd(&degB[esrc[i]], 1);
    }
  } else if (b < nbCount + nbP){
    mfma_gemm_body<128,4,true,true>(b - nbCount, pit, Wp, bp, px, NP, sWt);
  } else {
    mfma_gemm_body<128,4,true,true>(b - nbCount - nbP, bat, Wb, bb, bx, NB, sWt);
  }
}

// ---------------------------------------------------------------------------
// scan: shuffle-based exclusive scan, 4 elems/thread
// ---------------------------------------------------------------------------
__device__ void scan_dev(const int* __restrict__ deg, int* __restrict__ row_start,
                         int* __restrict__ cursor, int n){
  __shared__ int wsum[16];
  __shared__ int sbase;
  int t = threadIdx.x, w = t >> 6, l = t & 63;
  if (t == 0) sbase = 0;
  __syncthreads();
  for (int base = 0; base < n; base += 4096){
    int i = base + t*4;
    int4 v = make_int4(0,0,0,0);
    if (i < n) v = *(const int4*)(deg + i);
    int tsum = v.x + v.y + v.z + v.w;
    int x = tsum;
    #pragma unroll
    for (int off = 1; off < 64; off <<= 1){
      int y = __shfl_up(x, off);
      if (l >= off) x += y;
    }
    if (l == 63) wsum[w] = x;
    __syncthreads();
    int woff = 0, tot = 0;
    #pragma unroll
    for (int ww = 0; ww < 16; ++ww){
      int wv = wsum[ww];
      if (ww < w) woff += wv;
      tot += wv;
    }
    int excl = sbase + woff + x - tsum;
    if (i < n){
      int e1 = excl + v.x, e2 = excl + v.x + v.y, e3 = excl + v.x + v.y + v.z;
      row_start[i]   = excl; cursor[i]   = excl;
      row_start[i+1] = e1;   cursor[i+1] = e1;
      row_start[i+2] = e2;   cursor[i+2] = e2;
      row_start[i+3] = e3;   cursor[i+3] = e3;
    }
    __syncthreads();
    if (t == 0) sbase += tot;
    __syncthreads();
  }
  if (t == 0) row_start[n] = sbase;
}

__global__ __launch_bounds__(1024)
void scan2_kernel(const int* __restrict__ degA, int* __restrict__ rsA, int* __restrict__ curA, int nA,
                  const int* __restrict__ degB, int* __restrict__ rsB, int* __restrict__ curB, int nB,
                  float* __restrict__ mvec){
  if (blockIdx.x == 0){
    scan_dev(degA, rsA, curA, nA);
  } else {
    if (threadIdx.x < 144) mvec[threadIdx.x] = 0.f;   // zero mvec for colsum atomics
    scan_dev(degB, rsB, curB, nB);
  }
}

// ---------------------------------------------------------------------------
// k2: CSR scatter (both dirs) || all 4 GAT projection GEMMs merged.
// ---------------------------------------------------------------------------
__global__ __launch_bounds__(256)
void k2_scatter_proj(const int* __restrict__ edst, const int* __restrict__ esrc,
                     int* __restrict__ curA, int* __restrict__ curB,
                     int2* __restrict__ csrA, int2* __restrict__ csrB,
                     const unsigned short* __restrict__ px, const unsigned short* __restrict__ bx,
                     const float* __restrict__ rel_Wl, const float* __restrict__ rel_bl,
                     const float* __restrict__ rel_Wr, const float* __restrict__ rel_br,
                     const float* __restrict__ rev_Wl, const float* __restrict__ rev_bl,
                     const float* __restrict__ rev_Wr, const float* __restrict__ rev_br,
                     unsigned short* __restrict__ xlA, unsigned short* __restrict__ xrA,
                     unsigned short* __restrict__ xlB, unsigned short* __restrict__ xrB,
                     int nbScat, int nbP, int nbB)
{
  __shared__ unsigned short sWt[256*72];   // N=256, KP=72
  int b = blockIdx.x;
  if (b < nbScat){
    int i = b*256 + threadIdx.x;
    if (i < NEDGE){
      int d = edst[i], s = esrc[i];
      int p = atomicAdd(&curA[d], 1);
      csrA[p] = make_int2(i, s);
      int q = atomicAdd(&curB[s], 1);
      csrB[q] = make_int2(i, d);
    }
  } else {
    b -= nbScat;
    if (b < nbP)               mfma_gemm_body<64,16,false,false>(b,            px, rel_Wl, rel_bl, xlA, NP, sWt);
    else if (b < nbP + nbB)    mfma_gemm_body<64,16,false,false>(b-nbP,        bx, rel_Wr, rel_br, xrA, NB, sWt);
    else if (b < nbP + 2*nbB)  mfma_gemm_body<64,16,false,false>(b-nbP-nbB,    bx, rev_Wl, rev_bl, xlB, NB, sWt);
    else                       mfma_gemm_body<64,16,false,false>(b-nbP-2*nbB,  px, rev_Wr, rev_br, xrB, NP, sWt);
  }
}

// pair-compute for gat (see kernel): updates m,s,a0..a3 from regs
#define GAT_PAIR(X0, X1, EV0, EV1, V1OK, P0MASK)                             \
  {                                                                          \
    float x0 = b2f(X0.x), x1 = b2f(X0.y), x2 = b2f(X0.z), x3 = b2f(X0.w);    \
    float y0 = b2f(X1.x), y1 = b2f(X1.y), y2 = b2f(X1.z), y3 = b2f(X1.w);    \
    float h00 = x0 + r0, h01 = x1 + r1, h02 = x2 + r2, h03 = x3 + r3;        \
    float h10 = y0 + r0, h11 = y1 + r1, h12 = y2 + r2, h13 = y3 + r3;        \
    int ia0 = __float_as_int(EV0);                                           \
    int ia1 = __float_as_int(EV1);                                           \
    _Pragma("unroll")                                                        \
    for (int k = 0; k < EAD; ++k){                                           \
      float c0 = __int_as_float(__builtin_amdgcn_readlane(ia0, k));          \
      float c1 = __int_as_float(__builtin_amdgcn_readlane(ia1, k));          \
      float4 wv = *(const float4*)&sWe[k*CW + 4*l];                          \
      h00 = fmaf(c0, wv.x, h00); h01 = fmaf(c0, wv.y, h01);                  \
      h02 = fmaf(c0, wv.z, h02); h03 = fmaf(c0, wv.w, h03);                  \
      h10 = fmaf(c1, wv.x, h10); h11 = fmaf(c1, wv.y, h11);                  \
      h12 = fmaf(c1, wv.z, h12); h13 = fmaf(c1, wv.w, h13);                  \
    }                                                                        \
    h00 = (h00 > 0.f ? h00 : 0.2f*h00) * at.x;                               \
    h01 = (h01 > 0.f ? h01 : 0.2f*h01) * at.y;                               \
    h02 = (h02 > 0.f ? h02 : 0.2f*h02) * at.z;                               \
    h03 = (h03 > 0.f ? h03 : 0.2f*h03) * at.w;                               \
    h10 = (h10 > 0.f ? h10 : 0.2f*h10) * at.x;                               \
    h11 = (h11 > 0.f ? h11 : 0.2f*h11) * at.y;                               \
    h12 = (h12 > 0.f ? h12 : 0.2f*h12) * at.z;                               \
    h13 = (h13 > 0.f ? h13 : 0.2f*h13) * at.w;                               \
    float g0 = (h00 + h01) + (h02 + h03);                                    \
    float g1 = (h10 + h11) + (h12 + h13);                                    \
    _Pragma("unroll")                                                        \
    for (int off = 1; off < 16; off <<= 1){                                  \
      g0 += __shfl_xor(g0, off);                                             \
      g1 += __shfl_xor(g1, off);                                             \
    }                                                                        \
    float gm = (V1OK) ? fmaxf(g0, g1) : g0;                                  \
    float mn = fmaxf(m, gm);                                                 \
    float cc = __expf(m - mn);                                               \
    float p0 = __expf(g0 - mn);                                              \
    if (!(P0MASK)) p0 = 0.f;                                                 \
    float p1 = (V1OK) ? __expf(g1 - mn) : 0.f;                               \
    s  = fmaf(s, cc, p0 + p1);                                               \
    a0 = fmaf(a0, cc, fmaf(p1, y0, p0*x0));                                  \
    a1 = fmaf(a1, cc, fmaf(p1, y1, p0*x1));                                  \
    a2 = fmaf(a2, cc, fmaf(p1, y2, p0*x2));                                  \
    a3 = fmaf(a3, cc, fmaf(p1, y3, p0*x3));                                  \
    m = mn;                                                                  \
  }

// ---------------------------------------------------------------------------
// Merged fused GATv2 for BOTH directions in one launch (blockIdx partition).
// ---------------------------------------------------------------------------
__global__ __launch_bounds__(256)
void gat2_kernel(const unsigned short* __restrict__ xlA_, const unsigned short* __restrict__ xrA_,
                 const float* __restrict__ WeA, const float* __restrict__ attA,
                 const float* __restrict__ biasA, const int2* __restrict__ csrA_,
                 const int* __restrict__ rsA_, float* __restrict__ houtA,
                 const unsigned short* __restrict__ xlB_, const unsigned short* __restrict__ xrB_,
                 const float* __restrict__ WeB, const float* __restrict__ attB,
                 const float* __restrict__ biasB, const int2* __restrict__ csrB_,
                 const int* __restrict__ rsB_, float* __restrict__ houtB,
                 const float* __restrict__ ea, int gsplit)
{
  __shared__ float sWe[16*CW];
  bool isA = (int)blockIdx.x < gsplit;
  const unsigned short* xl = isA ? xlA_ : xlB_;
  const unsigned short* xr = isA ? xrA_ : xrB_;
  const float* We   = isA ? WeA   : WeB;
  const float* att  = isA ? attA  : attB;
  const float* bias = isA ? biasA : biasB;
  const int2* csr   = isA ? csrA_ : csrB_;
  const int* row_start = isA ? rsA_ : rsB_;
  float* hout = isA ? houtA : houtB;
  int ndst = isA ? NB : NP;
  int bid  = isA ? (int)blockIdx.x : (int)blockIdx.x - gsplit;
  int nblk = isA ? gsplit : (int)gridDim.x - gsplit;

  int t = threadIdx.x, l = t & 63;
  for (int i = t*4; i < 16*CW; i += 1024)
    *(float4*)&sWe[i] = *(const float4*)&We[i];
  __syncthreads();
  float4 at = *(const float4*)&att[4*l];
  float4 bi = *(const float4*)&bias[(l & 15)*4];
  int wid = bid*4 + (t >> 6);
  int nw = nblk*4;
  for (int d = wid; d < ndst; d += nw){
    ushort4 ru = *(const ushort4*)(xr + (size_t)d*CW + 4*l);
    float r0 = b2f(ru.x), r1 = b2f(ru.y), r2 = b2f(ru.z), r3 = b2f(ru.w);
    int rs = row_start[d], re = row_start[d+1];
    float m = -INFINITY, s = 0.f;
    float a0 = 0.f, a1 = 0.f, a2 = 0.f, a3 = 0.f;
    if (rs < re){
      int last = re - 1;
      #define CLMP(x) ((x) > last ? last : (x))
      int2 qA0 = csr[rs],         qA1 = csr[CLMP(rs+1)];
      int2 qB0 = csr[CLMP(rs+2)], qB1 = csr[CLMP(rs+3)];
      int2 nA0 = csr[CLMP(rs+4)], nA1 = csr[CLMP(rs+5)];
      int2 nB0 = csr[CLMP(rs+6)], nB1 = csr[CLMP(rs+7)];
      ushort4 xA0 = *(const ushort4*)(xl + (size_t)qA0.y*CW + 4*l);
      ushort4 xA1 = *(const ushort4*)(xl + (size_t)qA1.y*CW + 4*l);
      float  evA0 = ea[(size_t)qA0.x*EAD + (l & 15)];
      float  evA1 = ea[(size_t)qA1.x*EAD + (l & 15)];
      ushort4 xB0 = *(const ushort4*)(xl + (size_t)qB0.y*CW + 4*l);
      ushort4 xB1 = *(const ushort4*)(xl + (size_t)qB1.y*CW + 4*l);
      float  evB0 = ea[(size_t)qB0.x*EAD + (l & 15)];
      float  evB1 = ea[(size_t)qB1.x*EAD + (l & 15)];
      for (int i = rs; i < re; i += 4){
        int2 mA0 = csr[CLMP(i+8)],  mA1 = csr[CLMP(i+9)];
        int2 mB0 = csr[CLMP(i+10)], mB1 = csr[CLMP(i+11)];
        GAT_PAIR(xA0, xA1, evA0, evA1, (i+1 < re), true);
        xA0 = *(const ushort4*)(xl + (size_t)nA0.y*CW + 4*l);
        xA1 = *(const ushort4*)(xl + (size_t)nA1.y*CW + 4*l);
        evA0 = ea[(size_t)nA0.x*EAD + (l & 15)];
        evA1 = ea[(size_t)nA1.x*EAD + (l & 15)];
        nA0 = mA0; nA1 = mA1;
        GAT_PAIR(xB0, xB1, evB0, evB1, (i+3 < re), (i+2 < re));
        xB0 = *(const ushort4*)(xl + (size_t)nB0.y*CW + 4*l);
        xB1 = *(const ushort4*)(xl + (size_t)nB1.y*CW + 4*l);
        evB0 = ea[(size_t)nB0.x*EAD + (l & 15)];
        evB1 = ea[(size_t)nB1.x*EAD + (l & 15)];
        nB0 = mB0; nB1 = mB1;
      }
      #undef CLMP
    }
    float inv = 1.f / (s + 1e-16f);
    float v0 = a0*inv, v1 = a1*inv, v2 = a2*inv, v3 = a3*inv;
    v0 += __shfl_xor(v0, 16); v1 += __shfl_xor(v1, 16);
    v2 += __shfl_xor(v2, 16); v3 += __shfl_xor(v3, 16);
    v0 += __shfl_xor(v0, 32); v1 += __shfl_xor(v1, 32);
    v2 += __shfl_xor(v2, 32); v3 += __shfl_xor(v3, 32);
    if (l < 16){
      float4 o;
      o.x = geluf(v0*0.25f + bi.x);
      o.y = geluf(v1*0.25f + bi.y);
      o.z = geluf(v2*0.25f + bi.z);
      o.w = geluf(v3*0.25f + bi.w);
      *(float4*)(hout + (size_t)d*HID + 4*l) = o;
    }
  }
}

// ---------------------------------------------------------------------------
// k3: fused column means (mvec) || token-gather GEMM (cat -> @Wet) merged.
// ---------------------------------------------------------------------------
__device__ __forceinline__ void colsum_seg(int bid, int nb, const float4* __restrict__ in4,
                                           long total4, int n4, float* __restrict__ out,
                                           float scale, float* lds){
  int t = threadIdx.x, l = t & 63, w = t >> 6;
  long gid = (long)bid*256 + t;
  long stride = (long)nb*256;
  float4 acc = make_float4(0.f,0.f,0.f,0.f);
  for (long i = gid; i < total4; i += stride){
    float4 v = in4[i];
    acc.x += v.x; acc.y += v.y; acc.z += v.z; acc.w += v.w;
  }
  for (int off = n4; off < 64; off <<= 1){
    acc.x += __shfl_xor(acc.x, off);
    acc.y += __shfl_xor(acc.y, off);
    acc.z += __shfl_xor(acc.z, off);
    acc.w += __shfl_xor(acc.w, off);
  }
  if (l < n4) *(float4*)&lds[(w*n4 + l)*4] = acc;
  __syncthreads();
  if (t < n4*4){
    float sum = lds[t] + lds[n4*4 + t] + lds[2*n4*4 + t] + lds[3*n4*4 + t];
    atomicAdd(&out[t], sum * scale);
  }
  __syncthreads();
}

__device__ void colsum3_body(int bid, int nb, const float* __restrict__ hp,
                             const float* __restrict__ hb, const float* __restrict__ ea,
                             float* __restrict__ mvec){
  __shared__ float lds[4*16*4];
  colsum_seg(bid, nb, (const float4*)ea, (long)NEDGE*EAD/4, 4,  mvec+128, 1.f/NEDGE, lds);
  colsum_seg(bid, nb, (const float4*)hb, (long)NB*HID/4,    16, mvec+64,  1.f/NB,    lds);
  colsum_seg(bid, nb, (const float4*)hp, (long)NP*HID/4,    16, mvec,     1.f/NP,    lds);
}

__device__ void gemmcat_body(int bid, const float* __restrict__ hp, const float* __restrict__ hb,
                             const float* __restrict__ ea, const int* __restrict__ esrc,
                             const int* __restrict__ edst, const int* __restrict__ eids,
                             const float* __restrict__ W, const float* __restrict__ bias,
                             float* __restrict__ out)
{
  __shared__ float sAT[16][68];
  __shared__ float sB[16][68];
  __shared__ int sS[64], sD[64], sE[64];
  int t = threadIdx.x;
  int m0 = (bid >> 1)*64, n0 = (bid & 1)*64;
  if (t < 64){
    int e = eids[m0 + t];
    sS[t] = esrc[e]; sD[t] = edst[e]; sE[t] = e;
  }
  __syncthreads();
  int tr = t >> 4, tc = t & 15;
  float acc[4][4] = {};
  for (int k0 = 0; k0 < 144; k0 += 16){
    {
      int r = t >> 2, c = (t & 3) * 4;
      const float* src; int col = k0 + c;
      if (k0 < 64)       { src = hp + (size_t)sS[r]*HID; }
      else if (k0 < 128) { src = hb + (size_t)sD[r]*HID; col -= 64; }
      else               { src = ea + (size_t)sE[r]*EAD; col -= 128; }
      float4 va = *(const float4*)(src + col);
      sAT[c+0][r] = va.x; sAT[c+1][r] = va.y; sAT[c+2][r] = va.z; sAT[c+3][r] = va.w;
    }
    {
      int r = t >> 4, c = (t & 15) * 4;
      float4 vb = *(const float4*)(W + (size_t)(k0+r)*DD + n0 + c);
      *(float4*)&sB[r][c] = vb;
    }
    __syncthreads();
    #pragma unroll
    for (int k = 0; k < 16; ++k){
      float4 av = *(const float4*)&sAT[k][tr*4];
      float4 bv = *(const float4*)&sB[k][tc*4];
      acc[0][0] = fmaf(av.x, bv.x, acc[0][0]);
      acc[0][1] = fmaf(av.x, bv.y, acc[0][1]);
      acc[0][2] = fmaf(av.x, bv.z, acc[0][2]);
      acc[0][3] = fmaf(av.x, bv.w, acc[0][3]);
      acc[1][0] = fmaf(av.y, bv.x, acc[1][0]);
      acc[1][1] = fmaf(av.y, bv.y, acc[1][1]);
      acc[1][2] = fmaf(av.y, bv.z, acc[1][2]);
      acc[1][3] = fmaf(av.y, bv.w, acc[1][3]);
      acc[2][0] = fmaf(av.z, bv.x, acc[2][0]);
      acc[2][1] = fmaf(av.z, bv.y, acc[2][1]);
      acc[2][2] = fmaf(av.z, bv.z, acc[2][2]);
      acc[2][3] = fmaf(av.z, bv.w, acc[2][3]);
      acc[3][0] = fmaf(av.w, bv.x, acc[3][0]);
      acc[3][1] = fmaf(av.w, bv.y, acc[3][1]);
      acc[3][2] = fmaf(av.w, bv.z, acc[3][2]);
      acc[3][3] = fmaf(av.w, bv.w, acc[3][3]);
    }
    __syncthreads();
  }
  #pragma unroll
  for (int i = 0; i < 4; ++i){
    int gr = m0 + tr*4 + i;
    float4 v;
    v.x = acc[i][0] + bias[n0 + tc*4 + 0];
    v.y = acc[i][1] + bias[n0 + tc*4 + 1];
    v.z = acc[i][2] + bias[n0 + tc*4 + 2];
    v.w = acc[i][3] + bias[n0 + tc*4 + 3];
    *(float4*)(out + (size_t)gr*DD + n0 + tc*4) = v;
  }
}

__global__ __launch_bounds__(256)
void k3_colsum_gemmcat(const float* __restrict__ hp, const float* __restrict__ hb,
                       const float* __restrict__ ea, float* __restrict__ mvec,
                       const int* __restrict__ esrc, const int* __restrict__ edst,
                       const int* __restrict__ eids, const float* __restrict__ Wet,
                       const float* __restrict__ bet, float* __restrict__ tokb,
                       int nbCol)
{
  int b = blockIdx.x;
  if (b < nbCol) colsum3_body(b, nbCol, hp, hb, ea, mvec);
  else           gemmcat_body(b - nbCol, hp, hb, ea, esrc, edst, eids, Wet, bet, tokb);
}

// ---------------------------------------------------------------------------
// qstage: one (column-quad q, k-chunk ch) unit of a 6-row GEMM stage.
// W global row-major [K][N], x in LDS [6][K]. KC = K/NC must be 16.
// All 16 weight loads are independent float4 -> full MLP; partials reduced
// across the NC chunk lanes (consecutive in lane space) via shfl_xor.
// Per-lane k4 rotation de-conflicts the stride-16-word LDS reads.
// ---------------------------------------------------------------------------
template<int K, int N, int NC>
__device__ __forceinline__ void qstage(const float* __restrict__ x,
                                       const float* __restrict__ W,
                                       float (&a)[6][4], int q, int ch)
{
  constexpr int NQ = N/4;
  constexpr int KC = K/NC;   // = 16
  const float4* wp = (const float4*)W + (size_t)(ch*KC)*NQ + q;
  const float* xb = x + ch*KC;
  #pragma unroll
  for (int s = 0; s < 6; ++s){ a[s][0]=0.f; a[s][1]=0.f; a[s][2]=0.f; a[s][3]=0.f; }
  #pragma unroll
  for (int j = 0; j < 4; ++j){
    int k4 = (j + ch) & 3;
    float4 wv0 = wp[(size_t)(k4*4+0)*NQ];
    float4 wv1 = wp[(size_t)(k4*4+1)*NQ];
    float4 wv2 = wp[(size_t)(k4*4+2)*NQ];
    float4 wv3 = wp[(size_t)(k4*4+3)*NQ];
    #pragma unroll
    for (int s = 0; s < 6; ++s){
      float4 xv = *(const float4*)&xb[s*K + k4*4];
      a[s][0]=fmaf(xv.x,wv0.x,a[s][0]); a[s][0]=fmaf(xv.y,wv1.x,a[s][0]);
      a[s][0]=fmaf(xv.z,wv2.x,a[s][0]); a[s][0]=fmaf(xv.w,wv3.x,a[s][0]);
      a[s][1]=fmaf(xv.x,wv0.y,a[s][1]); a[s][1]=fmaf(xv.y,wv1.y,a[s][1]);
      a[s][1]=fmaf(xv.z,wv2.y,a[s][1]); a[s][1]=fmaf(xv.w,wv3.y,a[s][1]);
      a[s][2]=fmaf(xv.x,wv0.z,a[s][2]); a[s][2]=fmaf(xv.y,wv1.z,a[s][2]);
      a[s][2]=fmaf(xv.z,wv2.z,a[s][2]); a[s][2]=fmaf(xv.w,wv3.z,a[s][2]);
      a[s][3]=fmaf(xv.x,wv0.w,a[s][3]); a[s][3]=fmaf(xv.y,wv1.w,a[s][3]);
      a[s][3]=fmaf(xv.z,wv2.w,a[s][3]); a[s][3]=fmaf(xv.w,wv3.w,a[s][3]);
    }
  }
  #pragma unroll
  for (int off = 1; off < NC; off <<= 1){
    #pragma unroll
    for (int s = 0; s < 6; ++s){
      a[s][0]+=__shfl_xor(a[s][0],off); a[s][1]+=__shfl_xor(a[s][1],off);
      a[s][2]+=__shfl_xor(a[s][2],off); a[s][3]+=__shfl_xor(a[s][3],off);
    }
  }
}

// ---------------------------------------------------------------------------
// Fused transformer: buildx + 2 encoder layers + ctxdot in ONE block (512 thr).
// MLP-maximized: all weight reads are float4, 16 independent per unit; k-chunk
// partials reduced via wave shuffles. Writes only bias2.
// ---------------------------------------------------------------------------
__global__ __launch_bounds__(512)
void xform_kernel(const float* __restrict__ hist, const float* __restrict__ mvec,
                  const float* __restrict__ Wgs, const float* __restrict__ bgs,
                  const float* __restrict__ pos,
                  const float* __restrict__ Wqkv, const float* __restrict__ bqkv,
                  const float* __restrict__ Wo, const float* __restrict__ bo,
                  const float* __restrict__ ln1g, const float* __restrict__ ln1b,
                  const float* __restrict__ W1, const float* __restrict__ b1,
                  const float* __restrict__ W2, const float* __restrict__ b2,
                  const float* __restrict__ ln2g, const float* __restrict__ ln2b,
                  const float* __restrict__ Wc1, const float* __restrict__ bc1,
                  float* __restrict__ bias2)
{
  __shared__ float sx[SEQ*DD];       // current x
  __shared__ float sq[SEQ*3*DD];     // qkv
  __shared__ float sh[SEQ*512];      // ffn hidden / pre-LN1 buffer
  __shared__ float st[SEQ*DD];       // attn-out / pre-LN2 buffer
  __shared__ float sc[4][6][6];
  __shared__ float smean[SEQ], sinv[SEQ];
  __shared__ float smv[144];
  int t = threadIdx.x;

  // rows 0..4 = hist+pos ; mvec -> LDS
  for (int i = t; i < (SEQ-1)*DD; i += 512) sx[i] = hist[i] + pos[i];
  if (t < 144) smv[t] = mvec[t];
  __syncthreads();
  // row 5 = mvec @ Wgs + bgs + pos[5]   (32 quads x 8 chunks of 18 k)
  if (t < 256){
    int q = t >> 3, ch = t & 7;
    float a0=0.f,a1=0.f,a2=0.f,a3=0.f;
    #pragma unroll
    for (int kk = 0; kk < 18; ++kk){
      int k = ch*18 + kk;
      float4 wv = *(const float4*)&Wgs[k*DD + q*4];
      float xv = smv[k];
      a0=fmaf(xv,wv.x,a0); a1=fmaf(xv,wv.y,a1);
      a2=fmaf(xv,wv.z,a2); a3=fmaf(xv,wv.w,a3);
    }
    #pragma unroll
    for (int off = 1; off < 8; off <<= 1){
      a0+=__shfl_xor(a0,off); a1+=__shfl_xor(a1,off);
      a2+=__shfl_xor(a2,off); a3+=__shfl_xor(a3,off);
    }
    if (ch == 0){
      int n = q*4, base = (SEQ-1)*DD + n;
      sx[base+0]=a0+bgs[n+0]+pos[base+0];
      sx[base+1]=a1+bgs[n+1]+pos[base+1];
      sx[base+2]=a2+bgs[n+2]+pos[base+2];
      sx[base+3]=a3+bgs[n+3]+pos[base+3];
    }
  }
  __syncthreads();

  for (int lyr = 0; lyr < L; ++lyr){
    // qkv = x @ Wqkv + bqkv   (96 quads x 8 chunks = 768 units)
    {
      const float* wq = Wqkv + (size_t)lyr*DD*3*DD;
      const float* bq = bqkv + lyr*3*DD;
      for (int u = t; u < 768; u += 512){
        int q = u >> 3, ch = u & 7;
        float a[6][4];
        qstage<128,384,8>(sx, wq, a, q, ch);
        if (ch == 0){
          int n = q*4;
          #pragma unroll
          for (int s = 0; s < 6; ++s){
            sq[s*384+n+0]=a[s][0]+bq[n+0];
            sq[s*384+n+1]=a[s][1]+bq[n+1];
            sq[s*384+n+2]=a[s][2]+bq[n+2];
            sq[s*384+n+3]=a[s][3]+bq[n+3];
          }
        }
      }
    }
    __syncthreads();
    // scores
    if (t < 144){
      int h = t/36, r = t%36, qi = r/6, ki = r%6;
      float acc = 0.f;
      #pragma unroll
      for (int d2 = 0; d2 < 32; ++d2)
        acc = fmaf(sq[qi*384 + h*32 + d2], sq[ki*384 + 128 + h*32 + d2], acc);
      sc[h][qi][ki] = acc * 0.17677669529663687f;
    }
    __syncthreads();
    if (t < 24){
      int h = t/6, qi = t%6;
      float* row = sc[h][qi];
      float mx = row[0];
      #pragma unroll
      for (int k = 1; k < 6; ++k) mx = fmaxf(mx, row[k]);
      float sm = 0.f;
      #pragma unroll
      for (int k = 0; k < 6; ++k){ row[k] = __expf(row[k]-mx); sm += row[k]; }
      float inv = 1.f/sm;
      #pragma unroll
      for (int k = 0; k < 6; ++k) row[k] *= inv;
    }
    __syncthreads();
    // attention output -> st
    for (int i = t; i < SEQ*DD; i += 512){
      int s = i >> 7, n = i & 127, h = n >> 5, d2 = n & 31;
      float acc = 0.f;
      #pragma unroll
      for (int ki = 0; ki < 6; ++ki)
        acc = fmaf(sc[h][s][ki], sq[ki*384 + 256 + h*32 + d2], acc);
      st[i] = acc;
    }
    __syncthreads();
    // proj: st @ Wo + bo + resid(sx) -> sh   (32 quads x 8 chunks = 256 units)
    if (t < 256){
      int q = t >> 3, ch = t & 7;
      float a[6][4];
      qstage<128,128,8>(st, Wo + (size_t)lyr*DD*DD, a, q, ch);
      if (ch == 0){
        int n = q*4;
        const float* bop = bo + lyr*DD;
        #pragma unroll
        for (int s = 0; s < 6; ++s){
          sh[s*128+n+0]=a[s][0]+bop[n+0]+sx[s*128+n+0];
          sh[s*128+n+1]=a[s][1]+bop[n+1]+sx[s*128+n+1];
          sh[s*128+n+2]=a[s][2]+bop[n+2]+sx[s*128+n+2];
          sh[s*128+n+3]=a[s][3]+bop[n+3]+sx[s*128+n+3];
        }
      }
    }
    __syncthreads();
    // LN1: sh -> sx
    {
      int w = t >> 6, lw = t & 63;
      if (w < SEQ){
        float v0 = sh[w*DD + lw], v1 = sh[w*DD + 64 + lw];
        float sm = v0 + v1;
        #pragma unroll
        for (int off = 1; off < 64; off <<= 1) sm += __shfl_xor(sm, off);
        float mean = sm * 0.0078125f;
        float d0 = v0-mean, d1 = v1-mean;
        float qv = d0*d0 + d1*d1;
        #pragma unroll
        for (int off = 1; off < 64; off <<= 1) qv += __shfl_xor(qv, off);
        if (lw == 0){ smean[w] = mean; sinv[w] = rsqrtf(qv*0.0078125f + 1e-5f); }
      }
    }
    __syncthreads();
    {
      const float* g = ln1g + lyr*DD; const float* be = ln1b + lyr*DD;
      for (int i = t; i < SEQ*DD; i += 512){
        int s = i >> 7, n = i & 127;
        sx[i] = (sh[i]-smean[s])*sinv[s]*g[n] + be[n];
      }
    }
    __syncthreads();
    // ffn1: sx @ W1 -> gelu -> sh[6][512]   (128 quads x 8 chunks = 1024 units)
    {
      const float* w1 = W1 + (size_t)lyr*DD*512;
      const float* b1p = b1 + lyr*512;
      for (int u = t; u < 1024; u += 512){
        int q = u >> 3, ch = u & 7;
        float a[6][4];
        qstage<128,512,8>(sx, w1, a, q, ch);
        if (ch == 0){
          int n = q*4;
          #pragma unroll
          for (int s = 0; s < 6; ++s){
            sh[s*512+n+0]=geluf(a[s][0]+b1p[n+0]);
            sh[s*512+n+1]=geluf(a[s][1]+b1p[n+1]);
            sh[s*512+n+2]=geluf(a[s][2]+b1p[n+2]);
            sh[s*512+n+3]=geluf(a[s][3]+b1p[n+3]);
          }
        }
      }
    }
    __syncthreads();
    // ffn2: sh @ W2 + b2 + resid(sx) -> st   (32 quads x 32 chunks = 1024 units)
    {
      const float* w2 = W2 + (size_t)lyr*512*DD;
      const float* b2p = b2 + lyr*DD;
      for (int u = t; u < 1024; u += 512){
        int q = u >> 5, ch = u & 31;
        float a[6][4];
        qstage<512,128,32>(sh, w2, a, q, ch);
        if (ch == 0){
          int n = q*4;
          #pragma unroll
          for (int s = 0; s < 6; ++s){
            st[s*128+n+0]=a[s][0]+b2p[n+0]+sx[s*128+n+0];
            st[s*128+n+1]=a[s][1]+b2p[n+1]+sx[s*128+n+1];
            st[s*128+n+2]=a[s][2]+b2p[n+2]+sx[s*128+n+2];
            st[s*128+n+3]=a[s][3]+b2p[n+3]+sx[s*128+n+3];
          }
        }
      }
    }
    __syncthreads();
    // LN2: st -> sx
    {
      int w = t >> 6, lw = t & 63;
      if (w < SEQ){
        float v0 = st[w*DD + lw], v1 = st[w*DD + 64 + lw];
        float sm = v0 + v1;
        #pragma unroll
        for (int off = 1; off < 64; off <<= 1) sm += __shfl_xor(sm, off);
        float mean = sm * 0.0078125f;
        float d0 = v0-mean, d1 = v1-mean;
        float qv = d0*d0 + d1*d1;
        #pragma unroll
        for (int off = 1; off < 64; off <<= 1) qv += __shfl_xor(qv, off);
        if (lw == 0){ smean[w] = mean; sinv[w] = rsqrtf(qv*0.0078125f + 1e-5f); }
      }
    }
    __syncthreads();
    {
      const float* g = ln2g + lyr*DD; const float* be = ln2b + lyr*DD;
      for (int i = t; i < SEQ*DD; i += 512){
        int s = i >> 7, n = i & 127;
        sx[i] = (st[i]-smean[s])*sinv[s]*g[n] + be[n];
      }
    }
    __syncthreads();
  }
  // ctxdot: bias2[n] = bc1[n] + sum_k ctx[k]*Wc1[128+k][n]  (32 quads x 8 chunks)
  if (t < 256){
    int q = t >> 3, ch = t & 7;
    const float4* wp = (const float4*)(Wc1 + (size_t)DD*DD) + (size_t)(ch*16)*32 + q;
    const float* xb = &sx[(SEQ-1)*DD + ch*16];
    float a0=0.f,a1=0.f,a2=0.f,a3=0.f;
    #pragma unroll
    for (int kk = 0; kk < 16; ++kk){
      float4 wv = wp[(size_t)kk*32];
      float xv = xb[kk];
      a0=fmaf(xv,wv.x,a0); a1=fmaf(xv,wv.y,a1);
      a2=fmaf(xv,wv.z,a2); a3=fmaf(xv,wv.w,a3);
    }
    #pragma unroll
    for (int off = 1; off < 8; off <<= 1){
      a0+=__shfl_xor(a0,off); a1+=__shfl_xor(a1,off);
      a2+=__shfl_xor(a2,off); a3+=__shfl_xor(a3,off);
    }
    if (ch == 0){
      int n = q*4;
      bias2[n+0]=a0+bc1[n+0];
      bias2[n+1]=a1+bc1[n+1];
      bias2[n+2]=a2+bc1[n+2];
      bias2[n+3]=a3+bc1[n+3];
    }
  }
}

// ---------------------------------------------------------------------------
// Tiled GEMM (f32): hid = gelu(tokb @ Wc1[0:128] + bias2)
// ---------------------------------------------------------------------------
template<bool GELU>
__global__ __launch_bounds__(256)
void gemm64_kernel(const float* __restrict__ A, const float* __restrict__ W,
                   const float* __restrict__ bias, float* __restrict__ out,
                   int M, int K, int N)
{
  __shared__ float sAT[16][68];
  __shared__ float sB[16][68];
  int t = threadIdx.x;
  int m0 = blockIdx.x * 64, n0 = blockIdx.y * 64;
  int tr = t >> 4, tc = t & 15;
  float acc[4][4] = {};
  for (int k0 = 0; k0 < K; k0 += 16){
    {
      int r = t >> 2, c = (t & 3) * 4;
      int gr = m0 + r;
      float4 va = make_float4(0.f,0.f,0.f,0.f);
      if (gr < M) va = *(const float4*)(A + (size_t)gr*K + k0 + c);
      sAT[c+0][r] = va.x; sAT[c+1][r] = va.y; sAT[c+2][r] = va.z; sAT[c+3][r] = va.w;
    }
    {
      int r = t >> 4, c = (t & 15) * 4;
      float4 vb = *(const float4*)(W + (size_t)(k0+r)*N + n0 + c);
      *(float4*)&sB[r][c] = vb;
    }
    __syncthreads();
    #pragma unroll
    for (int k = 0; k < 16; ++k){
      float4 av = *(const float4*)&sAT[k][tr*4];
      float4 bv = *(const float4*)&sB[k][tc*4];
      acc[0][0] = fmaf(av.x, bv.x, acc[0][0]);
      acc[0][1] = fmaf(av.x, bv.y, acc[0][1]);
      acc[0][2] = fmaf(av.x, bv.z, acc[0][2]);
      acc[0][3] = fmaf(av.x, bv.w, acc[0][3]);
      acc[1][0] = fmaf(av.y, bv.x, acc[1][0]);
      acc[1][1] = fmaf(av.y, bv.y, acc[1][1]);
      acc[1][2] = fmaf(av.y, bv.z, acc[1][2]);
      acc[1][3] = fmaf(av.y, bv.w, acc[1][3]);
      acc[2][0] = fmaf(av.z, bv.x, acc[2][0]);
      acc[2][1] = fmaf(av.z, bv.y, acc[2][1]);
      acc[2][2] = fmaf(av.z, bv.z, acc[2][2]);
      acc[2][3] = fmaf(av.z, bv.w, acc[2][3]);
      acc[3][0] = fmaf(av.w, bv.x, acc[3][0]);
      acc[3][1] = fmaf(av.w, bv.y, acc[3][1]);
      acc[3][2] = fmaf(av.w, bv.z, acc[3][2]);
      acc[3][3] = fmaf(av.w, bv.w, acc[3][3]);
    }
    __syncthreads();
  }
  #pragma unroll
  for (int i = 0; i < 4; ++i){
    int gr = m0 + tr*4 + i;
    if (gr < M){
      float4 v;
      v.x = acc[i][0] + bias[n0 + tc*4 + 0];
      v.y = acc[i][1] + bias[n0 + tc*4 + 1];
      v.z = acc[i][2] + bias[n0 + tc*4 + 2];
      v.w = acc[i][3] + bias[n0 + tc*4 + 3];
      if (GELU){ v.x = geluf(v.x); v.y = geluf(v.y); v.z = geluf(v.z); v.w = geluf(v.w); }
      *(float4*)(out + (size_t)gr*N + n0 + tc*4) = v;
    }
  }
}

// out[i] = hid[i] @ Wc2 + bc2  (N=10), float4 hid reads
__global__ void head2_kernel(const float* __restrict__ hid, const float* __restrict__ Wc2,
                             const float* __restrict__ bc2, float* __restrict__ out){
  int i = blockIdx.x*blockDim.x + threadIdx.x;
  if (i >= BEDGE*16) return;
  int tok = i >> 4, c = i & 15;
  if (c < NCLS){
    float acc = bc2[c];
    const float4* hr4 = (const float4*)(hid + (size_t)tok*DD);
    #pragma unroll 8
    for (int k4 = 0; k4 < 32; ++k4){
      float4 hv = hr4[k4];
      acc = fmaf(hv.x, Wc2[(4*k4+0)*NCLS + c], acc);
      acc = fmaf(hv.y, Wc2[(4*k4+1)*NCLS + c], acc);
      acc = fmaf(hv.z, Wc2[(4*k4+2)*NCLS + c], acc);
      acc = fmaf(hv.w, Wc2[(4*k4+3)*NCLS + c], acc);
    }
    out[tok*NCLS + c] = acc;
  }
}

extern "C" void kernel_launch(void* const* d_in, const int* in_sizes, int n_in,
                              void* d_out, int out_size, void* d_ws, size_t ws_size,
                              hipStream_t stream){
  (void)in_sizes; (void)n_in; (void)out_size; (void)ws_size;
  const float* pitcher = (const float*)d_in[0];
  const float* batter  = (const float*)d_in[1];
  const float* eattr   = (const float*)d_in[2];
  const float* hist    = (const float*)d_in[3];
  const float* Wp = (const float*)d_in[4];
  const float* bp = (const float*)d_in[5];
  const float* Wb = (const float*)d_in[6];
  const float* bb = (const float*)d_in[7];
  const float* rel_Wl  = (const float*)d_in[8];
  const float* rel_bl  = (const float*)d_in[9];
  const float* rel_Wr  = (const float*)d_in[10];
  const float* rel_br  = (const float*)d_in[11];
  const float* rel_We  = (const float*)d_in[12];
  const float* rel_att = (const float*)d_in[13];
  const float* rel_bias= (const float*)d_in[14];
  const float* rev_Wl  = (const float*)d_in[15];
  const float* rev_bl  = (const float*)d_in[16];
  const float* rev_Wr  = (const float*)d_in[17];
  const float* rev_br  = (const float*)d_in[18];
  const float* rev_We  = (const float*)d_in[19];
  const float* rev_att = (const float*)d_in[20];
  const float* rev_bias= (const float*)d_in[21];
  const float* Wgs = (const float*)d_in[22];
  const float* bgs = (const float*)d_in[23];
  const float* Wet = (const float*)d_in[24];
  const float* bet = (const float*)d_in[25];
  const float* pos = (const float*)d_in[26];
  const float* Wqkv= (const float*)d_in[27];
  const float* bqkv= (const float*)d_in[28];
  const float* Wo  = (const float*)d_in[29];
  const float* bo  = (const float*)d_in[30];
  const float* ln1g= (const float*)d_in[31];
  const float* ln1b= (const float*)d_in[32];
  const float* W1  = (const float*)d_in[33];
  const float* b1  = (const float*)d_in[34];
  const float* W2  = (const float*)d_in[35];
  const float* b2  = (const float*)d_in[36];
  const float* ln2g= (const float*)d_in[37];
  const float* ln2b= (const float*)d_in[38];
  const float* Wc1 = (const float*)d_in[39];
  const float* bc1 = (const float*)d_in[40];
  const float* Wc2 = (const float*)d_in[41];
  const float* bc2 = (const float*)d_in[42];
  const int* esrc = (const int*)d_in[43];
  const int* edst = (const int*)d_in[44];
  const int* eids = (const int*)d_in[45];

  // workspace carve-out
  char* w = (char*)d_ws;
  size_t off = 0;
  auto alloc = [&](size_t bytes)->void*{
    void* p = (void*)(w + off);
    off += (bytes + 255) & ~(size_t)255;
    return p;
  };
  unsigned short* px_bf  = (unsigned short*)alloc((size_t)NP*HID*2);
  unsigned short* bx_bf  = (unsigned short*)alloc((size_t)NB*HID*2);
  float*          hp     = (float*)alloc((size_t)NP*HID*4);
  float*          hb     = (float*)alloc((size_t)NB*HID*4);
  unsigned short* xlA    = (unsigned short*)alloc((size_t)NP*CW*2);  // rel: src=pitcher
  unsigned short* xrA    = (unsigned short*)alloc((size_t)NB*CW*2);  // rel: dst=batter
  unsigned short* xlB    = (unsigned short*)alloc((size_t)NB*CW*2);  // rev: src=batter
  unsigned short* xrB    = (unsigned short*)alloc((size_t)NP*CW*2);  // rev: dst=pitcher
  int*            degAB  = (int*)alloc((size_t)(NB+NP)*4);
  int*            degA   = degAB;
  int*            degB   = degAB + NB;
  int*            rowstA = (int*)alloc((size_t)(NB+1)*4);
  int*            rowstB = (int*)alloc((size_t)(NP+1)*4);
  int*            cursA  = (int*)alloc((size_t)NB*4);
  int*            cursB  = (int*)alloc((size_t)NP*4);
  int2*           csrA   = (int2*)alloc((size_t)NEDGE*8);
  int2*           csrB   = (int2*)alloc((size_t)NEDGE*8);
  float*          mvec   = (float*)alloc(144*4);
  float*          bias2  = (float*)alloc(DD*4);
  // aliases over dead GAT buffers (xlA/xrA dead after gat2):
  float*          tokb   = (float*)xlA;   // BEDGE*DD*4 = 4.19MB <= 5.12MB
  float*          hid    = (float*)xrA;   // BEDGE*DD*4 <= 15.36MB

  const int nbCount = (NEDGE + 255)/256;          // 1172
  const int nbP = (NP + 63)/64;                   // 157
  const int nbB = (NB + 63)/64;                   // 469

  // k1: degree count (both dirs) || node encoders
  hipMemsetAsync(degAB, 0, (size_t)(NB+NP)*4, stream);
  k1_count_enc<<<nbCount + nbP + nbB, 256, 0, stream>>>(
      edst, esrc, degA, degB,
      pitcher, Wp, bp, px_bf, batter, Wb, bb, bx_bf, nbCount, nbP);

  // scan both CSRs (2 blocks) + zero mvec
  scan2_kernel<<<2, 1024, 0, stream>>>(degA, rowstA, cursA, NB,
                                       degB, rowstB, cursB, NP, mvec);

  // k2: CSR scatter || all four projection GEMMs
  k2_scatter_proj<<<nbCount + 2*nbP + 2*nbB, 256, 0, stream>>>(
      edst, esrc, cursA, cursB, csrA, csrB, px_bf, bx_bf,
      rel_Wl, rel_bl, rel_Wr, rel_br, rev_Wl, rev_bl, rev_Wr, rev_br,
      xlA, xrA, xlB, xrB, nbCount, nbP, nbB);

  // merged GAT, both directions in one launch
  gat2_kernel<<<4096, 256, 0, stream>>>(
      xlA, xrA, rel_We, rel_att, rel_bias, csrA, rowstA, hb,
      xlB, xrB, rev_We, rev_att, rev_bias, csrB, rowstB, hp,
      eattr, 2048);

  // k3: column means (mvec) || token-gather GEMM (tokb = cat @ Wet + bet)
  k3_colsum_gemmcat<<<512, 256, 0, stream>>>(
      hp, hb, eattr, mvec, esrc, edst, eids, Wet, bet, tokb, 256);

  // fused transformer (buildx + 2 layers + ctxdot) -> bias2
  xform_kernel<<<1, 512, 0, stream>>>(
      hist, mvec, Wgs, bgs, pos, Wqkv, bqkv, Wo, bo, ln1g, ln1b,
      W1, b1, W2, b2, ln2g, ln2b, Wc1, bc1, bias2);

  // classifier
  gemm64_kernel<true><<<dim3(BEDGE/64,2), 256, 0, stream>>>(tokb, Wc1, bias2, hid, BEDGE, DD, DD);
  head2_kernel<<<(BEDGE*16+255)/256, 256, 0, stream>>>(hid, Wc2, bc2, (float*)d_out);
}

// Round 3
// 387.323 us; speedup vs baseline: 1.4295x; 1.0822x over previous
//
#include <hip/hip_runtime.h>
#include <math.h>

// Problem constants (match reference)
#define NP 10000
#define NB 30000
#define NEDGE 300000
#define BEDGE 8192
#define EAD 16
#define HID 64
#define GH 4
#define CW 256      // GH*HID
#define DD 128
#define SEQ 6
#define NCLS 10
#define L 2

__device__ __forceinline__ float geluf(float x){
  // jax.nn.gelu(approximate=False)
  return 0.5f * x * (1.0f + erff(x * 0.7071067811865475f));
}

__device__ __forceinline__ float b2f(unsigned short u){
  unsigned v = ((unsigned)u) << 16;
  return __int_as_float(v);
}
__device__ __forceinline__ unsigned short f2b(float f){
  unsigned x = __float_as_uint(f);
  unsigned r = x + 0x7FFF + ((x >> 16) & 1);   // round-to-nearest-even
  return (unsigned short)(r >> 16);
}

typedef __attribute__((ext_vector_type(8))) short bf16x8;
typedef __attribute__((ext_vector_type(4))) float f32x4;

// ---------------------------------------------------------------------------
// MFMA GEMM body: out_bf16[M][N] = (GELU?)(A[M][KQ] @ W[KQ][N] + bias[N])
// ---------------------------------------------------------------------------
template<int KQ, int NTILES, bool A_F32, bool GELU>
__device__ __forceinline__
void mfma_gemm_body(int bid, const void* __restrict__ Av, const float* __restrict__ W,
                    const float* __restrict__ bias, unsigned short* __restrict__ out,
                    int M, unsigned short* __restrict__ sWt)
{
  constexpr int N  = NTILES * 16;
  constexpr int KP = KQ + 8;
  int t = threadIdx.x, w = t >> 6, l = t & 63;
  int c = l & 15, g = l >> 4;
  for (int idx = t; idx < KQ*N; idx += 256){
    int k = idx / N, n = idx - k*N;
    sWt[n*KP + k] = f2b(W[idx]);
  }
  __syncthreads();
  int rowbase = bid*64 + w*16;
  int arow = rowbase + c; if (arow > M-1) arow = M-1;   // clamp (no OOB reads)
  f32x4 acc[NTILES] = {};
  #pragma unroll
  for (int ks = 0; ks < KQ/32; ++ks){
    int koff = ks*32 + g*8;
    bf16x8 a;
    if constexpr (A_F32){
      const float* Af = (const float*)Av + (size_t)arow*KQ + koff;
      float4 f0 = *(const float4*)Af;
      float4 f1 = *(const float4*)(Af + 4);
      a[0]=(short)f2b(f0.x); a[1]=(short)f2b(f0.y); a[2]=(short)f2b(f0.z); a[3]=(short)f2b(f0.w);
      a[4]=(short)f2b(f1.x); a[5]=(short)f2b(f1.y); a[6]=(short)f2b(f1.z); a[7]=(short)f2b(f1.w);
    } else {
      a = *(const bf16x8*)((const unsigned short*)Av + (size_t)arow*KQ + koff);
    }
    #pragma unroll
    for (int nt = 0; nt < NTILES; ++nt){
      bf16x8 b = *(const bf16x8*)&sWt[(nt*16 + c)*KP + koff];
      acc[nt] = __builtin_amdgcn_mfma_f32_16x16x32_bf16(a, b, acc[nt], 0, 0, 0);
    }
  }
  #pragma unroll
  for (int nt = 0; nt < NTILES; ++nt){
    #pragma unroll
    for (int j = 0; j < 4; ++j){
      int row = rowbase + g*4 + j;
      if (row < M){
        int col = nt*16 + c;
        float v = acc[nt][j] + bias[col];
        if (GELU) v = geluf(v);
        out[(size_t)row*N + col] = f2b(v);
      }
    }
  }
}

// ---------------------------------------------------------------------------
// k1: edge-degree count (both dirs) || node encoders (pitcher+batter) merged.
// ---------------------------------------------------------------------------
__global__ __launch_bounds__(256)
void k1_count_enc(const int* __restrict__ edst, const int* __restrict__ esrc,
                  int* __restrict__ degA, int* __restrict__ degB,
                  const float* __restrict__ pit, const float* __restrict__ Wp,
                  const float* __restrict__ bp, unsigned short* __restrict__ px,
                  const float* __restrict__ bat, const float* __restrict__ Wb,
                  const float* __restrict__ bb, unsigned short* __restrict__ bx,
                  int nbCount, int nbP)
{
  __shared__ unsigned short sWt[64*136];   // N=64, KP=136
  int b = blockIdx.x;
  if (b < nbCount){
    int i = b*256 + threadIdx.x;
    if (i < NEDGE){
      atomicAdd(&degA[edst[i]], 1);
      atomicAdd(&degB[esrc[i]], 1);
    }
  } else if (b < nbCount + nbP){
    mfma_gemm_body<128,4,true,true>(b - nbCount, pit, Wp, bp, px, NP, sWt);
  } else {
    mfma_gemm_body<128,4,true,true>(b - nbCount - nbP, bat, Wb, bb, bx, NB, sWt);
  }
}

// ---------------------------------------------------------------------------
// scan: shuffle-based exclusive scan, 4 elems/thread
// ---------------------------------------------------------------------------
__device__ void scan_dev(const int* __restrict__ deg, int* __restrict__ row_start,
                         int* __restrict__ cursor, int n){
  __shared__ int wsum[16];
  __shared__ int sbase;
  int t = threadIdx.x, w = t >> 6, l = t & 63;
  if (t == 0) sbase = 0;
  __syncthreads();
  for (int base = 0; base < n; base += 4096){
    int i = base + t*4;
    int4 v = make_int4(0,0,0,0);
    if (i < n) v = *(const int4*)(deg + i);
    int tsum = v.x + v.y + v.z + v.w;
    int x = tsum;
    #pragma unroll
    for (int off = 1; off < 64; off <<= 1){
      int y = __shfl_up(x, off);
      if (l >= off) x += y;
    }
    if (l == 63) wsum[w] = x;
    __syncthreads();
    int woff = 0, tot = 0;
    #pragma unroll
    for (int ww = 0; ww < 16; ++ww){
      int wv = wsum[ww];
      if (ww < w) woff += wv;
      tot += wv;
    }
    int excl = sbase + woff + x - tsum;
    if (i < n){
      int e1 = excl + v.x, e2 = excl + v.x + v.y, e3 = excl + v.x + v.y + v.z;
      row_start[i]   = excl; cursor[i]   = excl;
      row_start[i+1] = e1;   cursor[i+1] = e1;
      row_start[i+2] = e2;   cursor[i+2] = e2;
      row_start[i+3] = e3;   cursor[i+3] = e3;
    }
    __syncthreads();
    if (t == 0) sbase += tot;
    __syncthreads();
  }
  if (t == 0) row_start[n] = sbase;
}

__global__ __launch_bounds__(1024)
void scan2_kernel(const int* __restrict__ degA, int* __restrict__ rsA, int* __restrict__ curA, int nA,
                  const int* __restrict__ degB, int* __restrict__ rsB, int* __restrict__ curB, int nB,
                  float* __restrict__ mvec){
  if (blockIdx.x == 0){
    scan_dev(degA, rsA, curA, nA);
  } else {
    if (threadIdx.x < 144) mvec[threadIdx.x] = 0.f;   // zero mvec for colsum atomics
    scan_dev(degB, rsB, curB, nB);
  }
}

// ---------------------------------------------------------------------------
// k2: CSR scatter (both dirs) || all 4 GAT projection GEMMs merged.
// ---------------------------------------------------------------------------
__global__ __launch_bounds__(256)
void k2_scatter_proj(const int* __restrict__ edst, const int* __restrict__ esrc,
                     int* __restrict__ curA, int* __restrict__ curB,
                     int2* __restrict__ csrA, int2* __restrict__ csrB,
                     const unsigned short* __restrict__ px, const unsigned short* __restrict__ bx,
                     const float* __restrict__ rel_Wl, const float* __restrict__ rel_bl,
                     const float* __restrict__ rel_Wr, const float* __restrict__ rel_br,
                     const float* __restrict__ rev_Wl, const float* __restrict__ rev_bl,
                     const float* __restrict__ rev_Wr, const float* __restrict__ rev_br,
                     unsigned short* __restrict__ xlA, unsigned short* __restrict__ xrA,
                     unsigned short* __restrict__ xlB, unsigned short* __restrict__ xrB,
                     int nbScat, int nbP, int nbB)
{
  __shared__ unsigned short sWt[256*72];   // N=256, KP=72
  int b = blockIdx.x;
  if (b < nbScat){
    int i = b*256 + threadIdx.x;
    if (i < NEDGE){
      int d = edst[i], s = esrc[i];
      int p = atomicAdd(&curA[d], 1);
      csrA[p] = make_int2(i, s);
      int q = atomicAdd(&curB[s], 1);
      csrB[q] = make_int2(i, d);
    }
  } else {
    b -= nbScat;
    if (b < nbP)               mfma_gemm_body<64,16,false,false>(b,            px, rel_Wl, rel_bl, xlA, NP, sWt);
    else if (b < nbP + nbB)    mfma_gemm_body<64,16,false,false>(b-nbP,        bx, rel_Wr, rel_br, xrA, NB, sWt);
    else if (b < nbP + 2*nbB)  mfma_gemm_body<64,16,false,false>(b-nbP-nbB,    bx, rev_Wl, rev_bl, xlB, NB, sWt);
    else                       mfma_gemm_body<64,16,false,false>(b-nbP-2*nbB,  px, rev_Wr, rev_br, xrB, NP, sWt);
  }
}

// pair-compute for gat (see kernel): updates m,s,a0..a3 from regs
#define GAT_PAIR(X0, X1, EV0, EV1, V1OK, P0MASK)                             \
  {                                                                          \
    float x0 = b2f(X0.x), x1 = b2f(X0.y), x2 = b2f(X0.z), x3 = b2f(X0.w);    \
    float y0 = b2f(X1.x), y1 = b2f(X1.y), y2 = b2f(X1.z), y3 = b2f(X1.w);    \
    float h00 = x0 + r0, h01 = x1 + r1, h02 = x2 + r2, h03 = x3 + r3;        \
    float h10 = y0 + r0, h11 = y1 + r1, h12 = y2 + r2, h13 = y3 + r3;        \
    int ia0 = __float_as_int(EV0);                                           \
    int ia1 = __float_as_int(EV1);                                           \
    _Pragma("unroll")                                                        \
    for (int k = 0; k < EAD; ++k){                                           \
      float c0 = __int_as_float(__builtin_amdgcn_readlane(ia0, k));          \
      float c1 = __int_as_float(__builtin_amdgcn_readlane(ia1, k));          \
      float4 wv = *(const float4*)&sWe[k*CW + 4*l];                          \
      h00 = fmaf(c0, wv.x, h00); h01 = fmaf(c0, wv.y, h01);                  \
      h02 = fmaf(c0, wv.z, h02); h03 = fmaf(c0, wv.w, h03);                  \
      h10 = fmaf(c1, wv.x, h10); h11 = fmaf(c1, wv.y, h11);                  \
      h12 = fmaf(c1, wv.z, h12); h13 = fmaf(c1, wv.w, h13);                  \
    }                                                                        \
    h00 = (h00 > 0.f ? h00 : 0.2f*h00) * at.x;                               \
    h01 = (h01 > 0.f ? h01 : 0.2f*h01) * at.y;                               \
    h02 = (h02 > 0.f ? h02 : 0.2f*h02) * at.z;                               \
    h03 = (h03 > 0.f ? h03 : 0.2f*h03) * at.w;                               \
    h10 = (h10 > 0.f ? h10 : 0.2f*h10) * at.x;                               \
    h11 = (h11 > 0.f ? h11 : 0.2f*h11) * at.y;                               \
    h12 = (h12 > 0.f ? h12 : 0.2f*h12) * at.z;                               \
    h13 = (h13 > 0.f ? h13 : 0.2f*h13) * at.w;                               \
    float g0 = (h00 + h01) + (h02 + h03);                                    \
    float g1 = (h10 + h11) + (h12 + h13);                                    \
    _Pragma("unroll")                                                        \
    for (int off = 1; off < 16; off <<= 1){                                  \
      g0 += __shfl_xor(g0, off);                                             \
      g1 += __shfl_xor(g1, off);                                             \
    }                                                                        \
    float gm = (V1OK) ? fmaxf(g0, g1) : g0;                                  \
    float mn = fmaxf(m, gm);                                                 \
    float cc = __expf(m - mn);                                               \
    float p0 = __expf(g0 - mn);                                              \
    if (!(P0MASK)) p0 = 0.f;                                                 \
    float p1 = (V1OK) ? __expf(g1 - mn) : 0.f;                               \
    s  = fmaf(s, cc, p0 + p1);                                               \
    a0 = fmaf(a0, cc, fmaf(p1, y0, p0*x0));                                  \
    a1 = fmaf(a1, cc, fmaf(p1, y1, p0*x1));                                  \
    a2 = fmaf(a2, cc, fmaf(p1, y2, p0*x2));                                  \
    a3 = fmaf(a3, cc, fmaf(p1, y3, p0*x3));                                  \
    m = mn;                                                                  \
  }

// ---------------------------------------------------------------------------
// Merged fused GATv2 for BOTH directions in one launch (blockIdx partition).
// ---------------------------------------------------------------------------
__global__ __launch_bounds__(256)
void gat2_kernel(const unsigned short* __restrict__ xlA_, const unsigned short* __restrict__ xrA_,
                 const float* __restrict__ WeA, const float* __restrict__ attA,
                 const float* __restrict__ biasA, const int2* __restrict__ csrA_,
                 const int* __restrict__ rsA_, float* __restrict__ houtA,
                 const unsigned short* __restrict__ xlB_, const unsigned short* __restrict__ xrB_,
                 const float* __restrict__ WeB, const float* __restrict__ attB,
                 const float* __restrict__ biasB, const int2* __restrict__ csrB_,
                 const int* __restrict__ rsB_, float* __restrict__ houtB,
                 const float* __restrict__ ea, int gsplit)
{
  __shared__ float sWe[16*CW];
  bool isA = (int)blockIdx.x < gsplit;
  const unsigned short* xl = isA ? xlA_ : xlB_;
  const unsigned short* xr = isA ? xrA_ : xrB_;
  const float* We   = isA ? WeA   : WeB;
  const float* att  = isA ? attA  : attB;
  const float* bias = isA ? biasA : biasB;
  const int2* csr   = isA ? csrA_ : csrB_;
  const int* row_start = isA ? rsA_ : rsB_;
  float* hout = isA ? houtA : houtB;
  int ndst = isA ? NB : NP;
  int bid  = isA ? (int)blockIdx.x : (int)blockIdx.x - gsplit;
  int nblk = isA ? gsplit : (int)gridDim.x - gsplit;

  int t = threadIdx.x, l = t & 63;
  for (int i = t*4; i < 16*CW; i += 1024)
    *(float4*)&sWe[i] = *(const float4*)&We[i];
  __syncthreads();
  float4 at = *(const float4*)&att[4*l];
  float4 bi = *(const float4*)&bias[(l & 15)*4];
  int wid = bid*4 + (t >> 6);
  int nw = nblk*4;
  for (int d = wid; d < ndst; d += nw){
    ushort4 ru = *(const ushort4*)(xr + (size_t)d*CW + 4*l);
    float r0 = b2f(ru.x), r1 = b2f(ru.y), r2 = b2f(ru.z), r3 = b2f(ru.w);
    int rs = row_start[d], re = row_start[d+1];
    float m = -INFINITY, s = 0.f;
    float a0 = 0.f, a1 = 0.f, a2 = 0.f, a3 = 0.f;
    if (rs < re){
      int last = re - 1;
      #define CLMP(x) ((x) > last ? last : (x))
      int2 qA0 = csr[rs],         qA1 = csr[CLMP(rs+1)];
      int2 qB0 = csr[CLMP(rs+2)], qB1 = csr[CLMP(rs+3)];
      int2 nA0 = csr[CLMP(rs+4)], nA1 = csr[CLMP(rs+5)];
      int2 nB0 = csr[CLMP(rs+6)], nB1 = csr[CLMP(rs+7)];
      ushort4 xA0 = *(const ushort4*)(xl + (size_t)qA0.y*CW + 4*l);
      ushort4 xA1 = *(const ushort4*)(xl + (size_t)qA1.y*CW + 4*l);
      float  evA0 = ea[(size_t)qA0.x*EAD + (l & 15)];
      float  evA1 = ea[(size_t)qA1.x*EAD + (l & 15)];
      ushort4 xB0 = *(const ushort4*)(xl + (size_t)qB0.y*CW + 4*l);
      ushort4 xB1 = *(const ushort4*)(xl + (size_t)qB1.y*CW + 4*l);
      float  evB0 = ea[(size_t)qB0.x*EAD + (l & 15)];
      float  evB1 = ea[(size_t)qB1.x*EAD + (l & 15)];
      for (int i = rs; i < re; i += 4){
        int2 mA0 = csr[CLMP(i+8)],  mA1 = csr[CLMP(i+9)];
        int2 mB0 = csr[CLMP(i+10)], mB1 = csr[CLMP(i+11)];
        GAT_PAIR(xA0, xA1, evA0, evA1, (i+1 < re), true);
        xA0 = *(const ushort4*)(xl + (size_t)nA0.y*CW + 4*l);
        xA1 = *(const ushort4*)(xl + (size_t)nA1.y*CW + 4*l);
        evA0 = ea[(size_t)nA0.x*EAD + (l & 15)];
        evA1 = ea[(size_t)nA1.x*EAD + (l & 15)];
        nA0 = mA0; nA1 = mA1;
        GAT_PAIR(xB0, xB1, evB0, evB1, (i+3 < re), (i+2 < re));
        xB0 = *(const ushort4*)(xl + (size_t)nB0.y*CW + 4*l);
        xB1 = *(const ushort4*)(xl + (size_t)nB1.y*CW + 4*l);
        evB0 = ea[(size_t)nB0.x*EAD + (l & 15)];
        evB1 = ea[(size_t)nB1.x*EAD + (l & 15)];
        nB0 = mB0; nB1 = mB1;
      }
      #undef CLMP
    }
    float inv = 1.f / (s + 1e-16f);
    float v0 = a0*inv, v1 = a1*inv, v2 = a2*inv, v3 = a3*inv;
    v0 += __shfl_xor(v0, 16); v1 += __shfl_xor(v1, 16);
    v2 += __shfl_xor(v2, 16); v3 += __shfl_xor(v3, 16);
    v0 += __shfl_xor(v0, 32); v1 += __shfl_xor(v1, 32);
    v2 += __shfl_xor(v2, 32); v3 += __shfl_xor(v3, 32);
    if (l < 16){
      float4 o;
      o.x = geluf(v0*0.25f + bi.x);
      o.y = geluf(v1*0.25f + bi.y);
      o.z = geluf(v2*0.25f + bi.z);
      o.w = geluf(v3*0.25f + bi.w);
      *(float4*)(hout + (size_t)d*HID + 4*l) = o;
    }
  }
}

// ---------------------------------------------------------------------------
// k3: fused column means (mvec) || token-gather GEMM (cat -> @Wet) merged.
// ---------------------------------------------------------------------------
__device__ __forceinline__ void colsum_seg(int bid, int nb, const float4* __restrict__ in4,
                                           long total4, int n4, float* __restrict__ out,
                                           float scale, float* lds){
  int t = threadIdx.x, l = t & 63, w = t >> 6;
  long gid = (long)bid*256 + t;
  long stride = (long)nb*256;
  float4 acc = make_float4(0.f,0.f,0.f,0.f);
  for (long i = gid; i < total4; i += stride){
    float4 v = in4[i];
    acc.x += v.x; acc.y += v.y; acc.z += v.z; acc.w += v.w;
  }
  for (int off = n4; off < 64; off <<= 1){
    acc.x += __shfl_xor(acc.x, off);
    acc.y += __shfl_xor(acc.y, off);
    acc.z += __shfl_xor(acc.z, off);
    acc.w += __shfl_xor(acc.w, off);
  }
  if (l < n4) *(float4*)&lds[(w*n4 + l)*4] = acc;
  __syncthreads();
  if (t < n4*4){
    float sum = lds[t] + lds[n4*4 + t] + lds[2*n4*4 + t] + lds[3*n4*4 + t];
    atomicAdd(&out[t], sum * scale);
  }
  __syncthreads();
}

__device__ void colsum3_body(int bid, int nb, const float* __restrict__ hp,
                             const float* __restrict__ hb, const float* __restrict__ ea,
                             float* __restrict__ mvec){
  __shared__ float lds[4*16*4];
  colsum_seg(bid, nb, (const float4*)ea, (long)NEDGE*EAD/4, 4,  mvec+128, 1.f/NEDGE, lds);
  colsum_seg(bid, nb, (const float4*)hb, (long)NB*HID/4,    16, mvec+64,  1.f/NB,    lds);
  colsum_seg(bid, nb, (const float4*)hp, (long)NP*HID/4,    16, mvec,     1.f/NP,    lds);
}

__device__ void gemmcat_body(int bid, const float* __restrict__ hp, const float* __restrict__ hb,
                             const float* __restrict__ ea, const int* __restrict__ esrc,
                             const int* __restrict__ edst, const int* __restrict__ eids,
                             const float* __restrict__ W, const float* __restrict__ bias,
                             float* __restrict__ out)
{
  __shared__ float sAT[16][68];
  __shared__ float sB[16][68];
  __shared__ int sS[64], sD[64], sE[64];
  int t = threadIdx.x;
  int m0 = (bid >> 1)*64, n0 = (bid & 1)*64;
  if (t < 64){
    int e = eids[m0 + t];
    sS[t] = esrc[e]; sD[t] = edst[e]; sE[t] = e;
  }
  __syncthreads();
  int tr = t >> 4, tc = t & 15;
  float acc[4][4] = {};
  for (int k0 = 0; k0 < 144; k0 += 16){
    {
      int r = t >> 2, c = (t & 3) * 4;
      const float* src; int col = k0 + c;
      if (k0 < 64)       { src = hp + (size_t)sS[r]*HID; }
      else if (k0 < 128) { src = hb + (size_t)sD[r]*HID; col -= 64; }
      else               { src = ea + (size_t)sE[r]*EAD; col -= 128; }
      float4 va = *(const float4*)(src + col);
      sAT[c+0][r] = va.x; sAT[c+1][r] = va.y; sAT[c+2][r] = va.z; sAT[c+3][r] = va.w;
    }
    {
      int r = t >> 4, c = (t & 15) * 4;
      float4 vb = *(const float4*)(W + (size_t)(k0+r)*DD + n0 + c);
      *(float4*)&sB[r][c] = vb;
    }
    __syncthreads();
    #pragma unroll
    for (int k = 0; k < 16; ++k){
      float4 av = *(const float4*)&sAT[k][tr*4];
      float4 bv = *(const float4*)&sB[k][tc*4];
      acc[0][0] = fmaf(av.x, bv.x, acc[0][0]);
      acc[0][1] = fmaf(av.x, bv.y, acc[0][1]);
      acc[0][2] = fmaf(av.x, bv.z, acc[0][2]);
      acc[0][3] = fmaf(av.x, bv.w, acc[0][3]);
      acc[1][0] = fmaf(av.y, bv.x, acc[1][0]);
      acc[1][1] = fmaf(av.y, bv.y, acc[1][1]);
      acc[1][2] = fmaf(av.y, bv.z, acc[1][2]);
      acc[1][3] = fmaf(av.y, bv.w, acc[1][3]);
      acc[2][0] = fmaf(av.z, bv.x, acc[2][0]);
      acc[2][1] = fmaf(av.z, bv.y, acc[2][1]);
      acc[2][2] = fmaf(av.z, bv.z, acc[2][2]);
      acc[2][3] = fmaf(av.z, bv.w, acc[2][3]);
      acc[3][0] = fmaf(av.w, bv.x, acc[3][0]);
      acc[3][1] = fmaf(av.w, bv.y, acc[3][1]);
      acc[3][2] = fmaf(av.w, bv.z, acc[3][2]);
      acc[3][3] = fmaf(av.w, bv.w, acc[3][3]);
    }
    __syncthreads();
  }
  #pragma unroll
  for (int i = 0; i < 4; ++i){
    int gr = m0 + tr*4 + i;
    float4 v;
    v.x = acc[i][0] + bias[n0 + tc*4 + 0];
    v.y = acc[i][1] + bias[n0 + tc*4 + 1];
    v.z = acc[i][2] + bias[n0 + tc*4 + 2];
    v.w = acc[i][3] + bias[n0 + tc*4 + 3];
    *(float4*)(out + (size_t)gr*DD + n0 + tc*4) = v;
  }
}

__global__ __launch_bounds__(256)
void k3_colsum_gemmcat(const float* __restrict__ hp, const float* __restrict__ hb,
                       const float* __restrict__ ea, float* __restrict__ mvec,
                       const int* __restrict__ esrc, const int* __restrict__ edst,
                       const int* __restrict__ eids, const float* __restrict__ Wet,
                       const float* __restrict__ bet, float* __restrict__ tokb,
                       int nbCol)
{
  int b = blockIdx.x;
  if (b < nbCol) colsum3_body(b, nbCol, hp, hb, ea, mvec);
  else           gemmcat_body(b - nbCol, hp, hb, ea, esrc, edst, eids, Wet, bet, tokb);
}

// ---------------------------------------------------------------------------
// qstageF: one (column-quad q, k-chunk ch) unit of a 6-row GEMM stage.
// ALL KC weight float4 loads are issued up front into statically-indexed
// registers (full MLP); the chunk rotation is applied to ADDRESSES only
// (kx[j]), never to register indices, so nothing spills or serializes.
// Partials reduced across the NC chunk-lanes (consecutive) via shfl_xor.
// ---------------------------------------------------------------------------
template<int K, int N, int NC>
__device__ __forceinline__ void qstageF(const float* __restrict__ x,
                                        const float* __restrict__ W,
                                        float (&a)[6][4], int q, int ch)
{
  constexpr int NQ = N/4;
  constexpr int KC = K/NC;     // multiple of 4
  constexpr int J  = KC/4;     // power of 2
  const float4* wp = (const float4*)W + (size_t)(ch*KC)*NQ + q;
  const float* xb = x + ch*KC;
  float4 wv[KC];
  int kx[J];
  #pragma unroll
  for (int j = 0; j < J; ++j){
    int k4 = (j + ch) & (J-1);
    kx[j] = k4;
    wv[j*4+0] = wp[(size_t)(k4*4+0)*NQ];
    wv[j*4+1] = wp[(size_t)(k4*4+1)*NQ];
    wv[j*4+2] = wp[(size_t)(k4*4+2)*NQ];
    wv[j*4+3] = wp[(size_t)(k4*4+3)*NQ];
  }
  #pragma unroll
  for (int s = 0; s < 6; ++s){ a[s][0]=0.f; a[s][1]=0.f; a[s][2]=0.f; a[s][3]=0.f; }
  #pragma unroll
  for (int j = 0; j < J; ++j){
    #pragma unroll
    for (int s = 0; s < 6; ++s){
      float4 xv = *(const float4*)&xb[s*K + kx[j]*4];
      a[s][0]=fmaf(xv.x,wv[j*4+0].x,a[s][0]); a[s][0]=fmaf(xv.y,wv[j*4+1].x,a[s][0]);
      a[s][0]=fmaf(xv.z,wv[j*4+2].x,a[s][0]); a[s][0]=fmaf(xv.w,wv[j*4+3].x,a[s][0]);
      a[s][1]=fmaf(xv.x,wv[j*4+0].y,a[s][1]); a[s][1]=fmaf(xv.y,wv[j*4+1].y,a[s][1]);
      a[s][1]=fmaf(xv.z,wv[j*4+2].y,a[s][1]); a[s][1]=fmaf(xv.w,wv[j*4+3].y,a[s][1]);
      a[s][2]=fmaf(xv.x,wv[j*4+0].z,a[s][2]); a[s][2]=fmaf(xv.y,wv[j*4+1].z,a[s][2]);
      a[s][2]=fmaf(xv.z,wv[j*4+2].z,a[s][2]); a[s][2]=fmaf(xv.w,wv[j*4+3].z,a[s][2]);
      a[s][3]=fmaf(xv.x,wv[j*4+0].w,a[s][3]); a[s][3]=fmaf(xv.y,wv[j*4+1].w,a[s][3]);
      a[s][3]=fmaf(xv.z,wv[j*4+2].w,a[s][3]); a[s][3]=fmaf(xv.w,wv[j*4+3].w,a[s][3]);
    }
  }
  #pragma unroll
  for (int off = 1; off < NC; off <<= 1){
    #pragma unroll
    for (int s = 0; s < 6; ++s){
      a[s][0]+=__shfl_xor(a[s][0],off); a[s][1]+=__shfl_xor(a[s][1],off);
      a[s][2]+=__shfl_xor(a[s][2],off); a[s][3]+=__shfl_xor(a[s][3],off);
    }
  }
}

// ---------------------------------------------------------------------------
// Fused transformer: buildx + 2 encoder layers + ctxdot in ONE block (512 thr).
// Every GEMM stage is one-shot per thread with all weight loads in flight.
// ---------------------------------------------------------------------------
__global__ __launch_bounds__(512)
void xform_kernel(const float* __restrict__ hist, const float* __restrict__ mvec,
                  const float* __restrict__ Wgs, const float* __restrict__ bgs,
                  const float* __restrict__ pos,
                  const float* __restrict__ Wqkv, const float* __restrict__ bqkv,
                  const float* __restrict__ Wo, const float* __restrict__ bo,
                  const float* __restrict__ ln1g, const float* __restrict__ ln1b,
                  const float* __restrict__ W1, const float* __restrict__ b1,
                  const float* __restrict__ W2, const float* __restrict__ b2,
                  const float* __restrict__ ln2g, const float* __restrict__ ln2b,
                  const float* __restrict__ Wc1, const float* __restrict__ bc1,
                  float* __restrict__ bias2)
{
  __shared__ float sx[SEQ*DD];       // current x
  __shared__ float sq[SEQ*3*DD];     // qkv
  __shared__ float sh[SEQ*512];      // ffn hidden / pre-LN1 buffer
  __shared__ float st[SEQ*DD];       // attn-out / pre-LN2 buffer
  __shared__ float sc[4][6][6];
  __shared__ float smv[144];
  int t = threadIdx.x;

  // rows 0..4 = hist+pos ; mvec -> LDS
  for (int i = t; i < (SEQ-1)*DD; i += 512) sx[i] = hist[i] + pos[i];
  if (t < 144) smv[t] = mvec[t];
  __syncthreads();
  // row 5 = mvec @ Wgs + bgs + pos[5]   (32 quads x 8 chunks of 18 k)
  if (t < 256){
    int q = t >> 3, ch = t & 7;
    float4 wv[18];
    #pragma unroll
    for (int kk = 0; kk < 18; ++kk)
      wv[kk] = *(const float4*)&Wgs[(ch*18+kk)*DD + q*4];
    float a0=0.f,a1=0.f,a2=0.f,a3=0.f;
    #pragma unroll
    for (int kk = 0; kk < 18; ++kk){
      float xv = smv[ch*18+kk];
      a0=fmaf(xv,wv[kk].x,a0); a1=fmaf(xv,wv[kk].y,a1);
      a2=fmaf(xv,wv[kk].z,a2); a3=fmaf(xv,wv[kk].w,a3);
    }
    #pragma unroll
    for (int off = 1; off < 8; off <<= 1){
      a0+=__shfl_xor(a0,off); a1+=__shfl_xor(a1,off);
      a2+=__shfl_xor(a2,off); a3+=__shfl_xor(a3,off);
    }
    if (ch == 0){
      int n = q*4, base = (SEQ-1)*DD + n;
      sx[base+0]=a0+bgs[n+0]+pos[base+0];
      sx[base+1]=a1+bgs[n+1]+pos[base+1];
      sx[base+2]=a2+bgs[n+2]+pos[base+2];
      sx[base+3]=a3+bgs[n+3]+pos[base+3];
    }
  }
  __syncthreads();

  for (int lyr = 0; lyr < L; ++lyr){
    // qkv = x @ Wqkv + bqkv   (96 quads x NC=4 chunks = 384 units, 32 loads ea)
    if (t < 384){
      int q = t >> 2, ch = t & 3;
      const float* wq = Wqkv + (size_t)lyr*DD*3*DD;
      const float* bq = bqkv + lyr*3*DD;
      float a[6][4];
      qstageF<128,384,4>(sx, wq, a, q, ch);
      if (ch == 0){
        int n = q*4;
        #pragma unroll
        for (int s = 0; s < 6; ++s){
          sq[s*384+n+0]=a[s][0]+bq[n+0];
          sq[s*384+n+1]=a[s][1]+bq[n+1];
          sq[s*384+n+2]=a[s][2]+bq[n+2];
          sq[s*384+n+3]=a[s][3]+bq[n+3];
        }
      }
    }
    __syncthreads();
    // scores
    if (t < 144){
      int h = t/36, r = t%36, qi = r/6, ki = r%6;
      float acc = 0.f;
      #pragma unroll
      for (int d2 = 0; d2 < 32; ++d2)
        acc = fmaf(sq[qi*384 + h*32 + d2], sq[ki*384 + 128 + h*32 + d2], acc);
      sc[h][qi][ki] = acc * 0.17677669529663687f;
    }
    __syncthreads();
    if (t < 24){
      int h = t/6, qi = t%6;
      float* row = sc[h][qi];
      float mx = row[0];
      #pragma unroll
      for (int k = 1; k < 6; ++k) mx = fmaxf(mx, row[k]);
      float sm = 0.f;
      #pragma unroll
      for (int k = 0; k < 6; ++k){ row[k] = __expf(row[k]-mx); sm += row[k]; }
      float inv = 1.f/sm;
      #pragma unroll
      for (int k = 0; k < 6; ++k) row[k] *= inv;
    }
    __syncthreads();
    // attention output -> st
    for (int i = t; i < SEQ*DD; i += 512){
      int s = i >> 7, n = i & 127, h = n >> 5, d2 = n & 31;
      float acc = 0.f;
      #pragma unroll
      for (int ki = 0; ki < 6; ++ki)
        acc = fmaf(sc[h][s][ki], sq[ki*384 + 256 + h*32 + d2], acc);
      st[i] = acc;
    }
    __syncthreads();
    // proj: st @ Wo + bo + resid(sx) -> sh   (32 quads x NC=16 = 512 units, 8 loads)
    {
      int q = t >> 4, ch = t & 15;
      float a[6][4];
      qstageF<128,128,16>(st, Wo + (size_t)lyr*DD*DD, a, q, ch);
      if (ch == 0){
        int n = q*4;
        const float* bop = bo + lyr*DD;
        #pragma unroll
        for (int s = 0; s < 6; ++s){
          sh[s*128+n+0]=a[s][0]+bop[n+0]+sx[s*128+n+0];
          sh[s*128+n+1]=a[s][1]+bop[n+1]+sx[s*128+n+1];
          sh[s*128+n+2]=a[s][2]+bop[n+2]+sx[s*128+n+2];
          sh[s*128+n+3]=a[s][3]+bop[n+3]+sx[s*128+n+3];
        }
      }
    }
    __syncthreads();
    // LN1 (single phase): sh -> sx, one wave per row
    {
      int w = t >> 6, lw = t & 63;
      if (w < SEQ){
        const float* g = ln1g + lyr*DD; const float* be = ln1b + lyr*DD;
        float v0 = sh[w*DD + lw], v1 = sh[w*DD + 64 + lw];
        float sm = v0 + v1;
        #pragma unroll
        for (int off = 1; off < 64; off <<= 1) sm += __shfl_xor(sm, off);
        float mean = sm * 0.0078125f;
        float d0 = v0-mean, d1 = v1-mean;
        float qv = d0*d0 + d1*d1;
        #pragma unroll
        for (int off = 1; off < 64; off <<= 1) qv += __shfl_xor(qv, off);
        float inv = rsqrtf(qv*0.0078125f + 1e-5f);
        sx[w*DD + lw]      = d0*inv*g[lw] + be[lw];
        sx[w*DD + 64 + lw] = d1*inv*g[64+lw] + be[64+lw];
      }
    }
    __syncthreads();
    // ffn1: sx @ W1 -> gelu -> sh[6][512]   (128 quads x NC=4 = 512 units, 32 loads)
    {
      int q = t >> 2, ch = t & 3;
      const float* w1 = W1 + (size_t)lyr*DD*512;
      const float* b1p = b1 + lyr*512;
      float a[6][4];
      qstageF<128,512,4>(sx, w1, a, q, ch);
      if (ch == 0){
        int n = q*4;
        #pragma unroll
        for (int s = 0; s < 6; ++s){
          sh[s*512+n+0]=geluf(a[s][0]+b1p[n+0]);
          sh[s*512+n+1]=geluf(a[s][1]+b1p[n+1]);
          sh[s*512+n+2]=geluf(a[s][2]+b1p[n+2]);
          sh[s*512+n+3]=geluf(a[s][3]+b1p[n+3]);
        }
      }
    }
    __syncthreads();
    // ffn2: sh @ W2 + b2 + resid(sx) -> st   (32 quads x NC=16 = 512 units, 32 loads)
    {
      int q = t >> 4, ch = t & 15;
      const float* w2 = W2 + (size_t)lyr*512*DD;
      const float* b2p = b2 + lyr*DD;
      float a[6][4];
      qstageF<512,128,16>(sh, w2, a, q, ch);
      if (ch == 0){
        int n = q*4;
        #pragma unroll
        for (int s = 0; s < 6; ++s){
          st[s*128+n+0]=a[s][0]+b2p[n+0]+sx[s*128+n+0];
          st[s*128+n+1]=a[s][1]+b2p[n+1]+sx[s*128+n+1];
          st[s*128+n+2]=a[s][2]+b2p[n+2]+sx[s*128+n+2];
          st[s*128+n+3]=a[s][3]+b2p[n+3]+sx[s*128+n+3];
        }
      }
    }
    __syncthreads();
    // LN2 (single phase): st -> sx
    {
      int w = t >> 6, lw = t & 63;
      if (w < SEQ){
        const float* g = ln2g + lyr*DD; const float* be = ln2b + lyr*DD;
        float v0 = st[w*DD + lw], v1 = st[w*DD + 64 + lw];
        float sm = v0 + v1;
        #pragma unroll
        for (int off = 1; off < 64; off <<= 1) sm += __shfl_xor(sm, off);
        float mean = sm * 0.0078125f;
        float d0 = v0-mean, d1 = v1-mean;
        float qv = d0*d0 + d1*d1;
        #pragma unroll
        for (int off = 1; off < 64; off <<= 1) qv += __shfl_xor(qv, off);
        float inv = rsqrtf(qv*0.0078125f + 1e-5f);
        sx[w*DD + lw]      = d0*inv*g[lw] + be[lw];
        sx[w*DD + 64 + lw] = d1*inv*g[64+lw] + be[64+lw];
      }
    }
    __syncthreads();
  }
  // ctxdot: bias2[n] = bc1[n] + sum_k ctx[k]*Wc1[128+k][n]  (32 quads x 8 chunks)
  if (t < 256){
    int q = t >> 3, ch = t & 7;
    const float4* wp = (const float4*)(Wc1 + (size_t)DD*DD) + (size_t)(ch*16)*32 + q;
    const float* xb = &sx[(SEQ-1)*DD + ch*16];
    float4 wv[16];
    int kx[4];
    #pragma unroll
    for (int j = 0; j < 4; ++j){
      int k4 = (j + ch) & 3;
      kx[j] = k4;
      wv[j*4+0] = wp[(size_t)(k4*4+0)*32];
      wv[j*4+1] = wp[(size_t)(k4*4+1)*32];
      wv[j*4+2] = wp[(size_t)(k4*4+2)*32];
      wv[j*4+3] = wp[(size_t)(k4*4+3)*32];
    }
    float a0=0.f,a1=0.f,a2=0.f,a3=0.f;
    #pragma unroll
    for (int j = 0; j < 4; ++j){
      float4 xv = *(const float4*)&xb[kx[j]*4];
      a0=fmaf(xv.x,wv[j*4+0].x,a0); a0=fmaf(xv.y,wv[j*4+1].x,a0);
      a0=fmaf(xv.z,wv[j*4+2].x,a0); a0=fmaf(xv.w,wv[j*4+3].x,a0);
      a1=fmaf(xv.x,wv[j*4+0].y,a1); a1=fmaf(xv.y,wv[j*4+1].y,a1);
      a1=fmaf(xv.z,wv[j*4+2].y,a1); a1=fmaf(xv.w,wv[j*4+3].y,a1);
      a2=fmaf(xv.x,wv[j*4+0].z,a2); a2=fmaf(xv.y,wv[j*4+1].z,a2);
      a2=fmaf(xv.z,wv[j*4+2].z,a2); a2=fmaf(xv.w,wv[j*4+3].z,a2);
      a3=fmaf(xv.x,wv[j*4+0].w,a3); a3=fmaf(xv.y,wv[j*4+1].w,a3);
      a3=fmaf(xv.z,wv[j*4+2].w,a3); a3=fmaf(xv.w,wv[j*4+3].w,a3);
    }
    #pragma unroll
    for (int off = 1; off < 8; off <<= 1){
      a0+=__shfl_xor(a0,off); a1+=__shfl_xor(a1,off);
      a2+=__shfl_xor(a2,off); a3+=__shfl_xor(a3,off);
    }
    if (ch == 0){
      int n = q*4;
      bias2[n+0]=a0+bc1[n+0];
      bias2[n+1]=a1+bc1[n+1];
      bias2[n+2]=a2+bc1[n+2];
      bias2[n+3]=a3+bc1[n+3];
    }
  }
}

// ---------------------------------------------------------------------------
// Tiled GEMM (f32): hid = gelu(tokb @ Wc1[0:128] + bias2)
// ---------------------------------------------------------------------------
template<bool GELU>
__global__ __launch_bounds__(256)
void gemm64_kernel(const float* __restrict__ A, const float* __restrict__ W,
                   const float* __restrict__ bias, float* __restrict__ out,
                   int M, int K, int N)
{
  __shared__ float sAT[16][68];
  __shared__ float sB[16][68];
  int t = threadIdx.x;
  int m0 = blockIdx.x * 64, n0 = blockIdx.y * 64;
  int tr = t >> 4, tc = t & 15;
  float acc[4][4] = {};
  for (int k0 = 0; k0 < K; k0 += 16){
    {
      int r = t >> 2, c = (t & 3) * 4;
      int gr = m0 + r;
      float4 va = make_float4(0.f,0.f,0.f,0.f);
      if (gr < M) va = *(const float4*)(A + (size_t)gr*K + k0 + c);
      sAT[c+0][r] = va.x; sAT[c+1][r] = va.y; sAT[c+2][r] = va.z; sAT[c+3][r] = va.w;
    }
    {
      int r = t >> 4, c = (t & 15) * 4;
      float4 vb = *(const float4*)(W + (size_t)(k0+r)*N + n0 + c);
      *(float4*)&sB[r][c] = vb;
    }
    __syncthreads();
    #pragma unroll
    for (int k = 0; k < 16; ++k){
      float4 av = *(const float4*)&sAT[k][tr*4];
      float4 bv = *(const float4*)&sB[k][tc*4];
      acc[0][0] = fmaf(av.x, bv.x, acc[0][0]);
      acc[0][1] = fmaf(av.x, bv.y, acc[0][1]);
      acc[0][2] = fmaf(av.x, bv.z, acc[0][2]);
      acc[0][3] = fmaf(av.x, bv.w, acc[0][3]);
      acc[1][0] = fmaf(av.y, bv.x, acc[1][0]);
      acc[1][1] = fmaf(av.y, bv.y, acc[1][1]);
      acc[1][2] = fmaf(av.y, bv.z, acc[1][2]);
      acc[1][3] = fmaf(av.y, bv.w, acc[1][3]);
      acc[2][0] = fmaf(av.z, bv.x, acc[2][0]);
      acc[2][1] = fmaf(av.z, bv.y, acc[2][1]);
      acc[2][2] = fmaf(av.z, bv.z, acc[2][2]);
      acc[2][3] = fmaf(av.z, bv.w, acc[2][3]);
      acc[3][0] = fmaf(av.w, bv.x, acc[3][0]);
      acc[3][1] = fmaf(av.w, bv.y, acc[3][1]);
      acc[3][2] = fmaf(av.w, bv.z, acc[3][2]);
      acc[3][3] = fmaf(av.w, bv.w, acc[3][3]);
    }
    __syncthreads();
  }
  #pragma unroll
  for (int i = 0; i < 4; ++i){
    int gr = m0 + tr*4 + i;
    if (gr < M){
      float4 v;
      v.x = acc[i][0] + bias[n0 + tc*4 + 0];
      v.y = acc[i][1] + bias[n0 + tc*4 + 1];
      v.z = acc[i][2] + bias[n0 + tc*4 + 2];
      v.w = acc[i][3] + bias[n0 + tc*4 + 3];
      if (GELU){ v.x = geluf(v.x); v.y = geluf(v.y); v.z = geluf(v.z); v.w = geluf(v.w); }
      *(float4*)(out + (size_t)gr*N + n0 + tc*4) = v;
    }
  }
}

// out[i] = hid[i] @ Wc2 + bc2  (N=10), float4 hid reads
__global__ void head2_kernel(const float* __restrict__ hid, const float* __restrict__ Wc2,
                             const float* __restrict__ bc2, float* __restrict__ out){
  int i = blockIdx.x*blockDim.x + threadIdx.x;
  if (i >= BEDGE*16) return;
  int tok = i >> 4, c = i & 15;
  if (c < NCLS){
    float acc = bc2[c];
    const float4* hr4 = (const float4*)(hid + (size_t)tok*DD);
    #pragma unroll 8
    for (int k4 = 0; k4 < 32; ++k4){
      float4 hv = hr4[k4];
      acc = fmaf(hv.x, Wc2[(4*k4+0)*NCLS + c], acc);
      acc = fmaf(hv.y, Wc2[(4*k4+1)*NCLS + c], acc);
      acc = fmaf(hv.z, Wc2[(4*k4+2)*NCLS + c], acc);
      acc = fmaf(hv.w, Wc2[(4*k4+3)*NCLS + c], acc);
    }
    out[tok*NCLS + c] = acc;
  }
}

extern "C" void kernel_launch(void* const* d_in, const int* in_sizes, int n_in,
                              void* d_out, int out_size, void* d_ws, size_t ws_size,
                              hipStream_t stream){
  (void)in_sizes; (void)n_in; (void)out_size; (void)ws_size;
  const float* pitcher = (const float*)d_in[0];
  const float* batter  = (const float*)d_in[1];
  const float* eattr   = (const float*)d_in[2];
  const float* hist    = (const float*)d_in[3];
  const float* Wp = (const float*)d_in[4];
  const float* bp = (const float*)d_in[5];
  const float* Wb = (const float*)d_in[6];
  const float* bb = (const float*)d_in[7];
  const float* rel_Wl  = (const float*)d_in[8];
  const float* rel_bl  = (const float*)d_in[9];
  const float* rel_Wr  = (const float*)d_in[10];
  const float* rel_br  = (const float*)d_in[11];
  const float* rel_We  = (const float*)d_in[12];
  const float* rel_att = (const float*)d_in[13];
  const float* rel_bias= (const float*)d_in[14];
  const float* rev_Wl  = (const float*)d_in[15];
  const float* rev_bl  = (const float*)d_in[16];
  const float* rev_Wr  = (const float*)d_in[17];
  const float* rev_br  = (const float*)d_in[18];
  const float* rev_We  = (const float*)d_in[19];
  const float* rev_att = (const float*)d_in[20];
  const float* rev_bias= (const float*)d_in[21];
  const float* Wgs = (const float*)d_in[22];
  const float* bgs = (const float*)d_in[23];
  const float* Wet = (const float*)d_in[24];
  const float* bet = (const float*)d_in[25];
  const float* pos = (const float*)d_in[26];
  const float* Wqkv= (const float*)d_in[27];
  const float* bqkv= (const float*)d_in[28];
  const float* Wo  = (const float*)d_in[29];
  const float* bo  = (const float*)d_in[30];
  const float* ln1g= (const float*)d_in[31];
  const float* ln1b= (const float*)d_in[32];
  const float* W1  = (const float*)d_in[33];
  const float* b1  = (const float*)d_in[34];
  const float* W2  = (const float*)d_in[35];
  const float* b2  = (const float*)d_in[36];
  const float* ln2g= (const float*)d_in[37];
  const float* ln2b= (const float*)d_in[38];
  const float* Wc1 = (const float*)d_in[39];
  const float* bc1 = (const float*)d_in[40];
  const float* Wc2 = (const float*)d_in[41];
  const float* bc2 = (const float*)d_in[42];
  const int* esrc = (const int*)d_in[43];
  const int* edst = (const int*)d_in[44];
  const int* eids = (const int*)d_in[45];

  // workspace carve-out
  char* w = (char*)d_ws;
  size_t off = 0;
  auto alloc = [&](size_t bytes)->void*{
    void* p = (void*)(w + off);
    off += (bytes + 255) & ~(size_t)255;
    return p;
  };
  unsigned short* px_bf  = (unsigned short*)alloc((size_t)NP*HID*2);
  unsigned short* bx_bf  = (unsigned short*)alloc((size_t)NB*HID*2);
  float*          hp     = (float*)alloc((size_t)NP*HID*4);
  float*          hb     = (float*)alloc((size_t)NB*HID*4);
  unsigned short* xlA    = (unsigned short*)alloc((size_t)NP*CW*2);  // rel: src=pitcher
  unsigned short* xrA    = (unsigned short*)alloc((size_t)NB*CW*2);  // rel: dst=batter
  unsigned short* xlB    = (unsigned short*)alloc((size_t)NB*CW*2);  // rev: src=batter
  unsigned short* xrB    = (unsigned short*)alloc((size_t)NP*CW*2);  // rev: dst=pitcher
  int*            degAB  = (int*)alloc((size_t)(NB+NP)*4);
  int*            degA   = degAB;
  int*            degB   = degAB + NB;
  int*            rowstA = (int*)alloc((size_t)(NB+1)*4);
  int*            rowstB = (int*)alloc((size_t)(NP+1)*4);
  int*            cursA  = (int*)alloc((size_t)NB*4);
  int*            cursB  = (int*)alloc((size_t)NP*4);
  int2*           csrA   = (int2*)alloc((size_t)NEDGE*8);
  int2*           csrB   = (int2*)alloc((size_t)NEDGE*8);
  float*          mvec   = (float*)alloc(144*4);
  float*          bias2  = (float*)alloc(DD*4);
  // aliases over dead GAT buffers (xlA/xrA dead after gat2):
  float*          tokb   = (float*)xlA;   // BEDGE*DD*4 = 4.19MB <= 5.12MB
  float*          hid    = (float*)xrA;   // BEDGE*DD*4 <= 15.36MB

  const int nbCount = (NEDGE + 255)/256;          // 1172
  const int nbP = (NP + 63)/64;                   // 157
  const int nbB = (NB + 63)/64;                   // 469

  // k1: degree count (both dirs) || node encoders
  hipMemsetAsync(degAB, 0, (size_t)(NB+NP)*4, stream);
  k1_count_enc<<<nbCount + nbP + nbB, 256, 0, stream>>>(
      edst, esrc, degA, degB,
      pitcher, Wp, bp, px_bf, batter, Wb, bb, bx_bf, nbCount, nbP);

  // scan both CSRs (2 blocks) + zero mvec
  scan2_kernel<<<2, 1024, 0, stream>>>(degA, rowstA, cursA, NB,
                                       degB, rowstB, cursB, NP, mvec);

  // k2: CSR scatter || all four projection GEMMs
  k2_scatter_proj<<<nbCount + 2*nbP + 2*nbB, 256, 0, stream>>>(
      edst, esrc, cursA, cursB, csrA, csrB, px_bf, bx_bf,
      rel_Wl, rel_bl, rel_Wr, rel_br, rev_Wl, rev_bl, rev_Wr, rev_br,
      xlA, xrA, xlB, xrB, nbCount, nbP, nbB);

  // merged GAT, both directions in one launch
  gat2_kernel<<<4096, 256, 0, stream>>>(
      xlA, xrA, rel_We, rel_att, rel_bias, csrA, rowstA, hb,
      xlB, xrB, rev_We, rev_att, rev_bias, csrB, rowstB, hp,
      eattr, 2048);

  // k3: column means (mvec) || token-gather GEMM (tokb = cat @ Wet + bet)
  k3_colsum_gemmcat<<<512, 256, 0, stream>>>(
      hp, hb, eattr, mvec, esrc, edst, eids, Wet, bet, tokb, 256);

  // fused transformer (buildx + 2 layers + ctxdot) -> bias2
  xform_kernel<<<1, 512, 0, stream>>>(
      hist, mvec, Wgs, bgs, pos, Wqkv, bqkv, Wo, bo, ln1g, ln1b,
      W1, b1, W2, b2, ln2g, ln2b, Wc1, bc1, bias2);

  // classifier
  gemm64_kernel<true><<<dim3(BEDGE/64,2), 256, 0, stream>>>(tokb, Wc1, bias2, hid, BEDGE, DD, DD);
  head2_kernel<<<(BEDGE*16+255)/256, 256, 0, stream>>>(hid, Wc2, bc2, (float*)d_out);
}